// Round 9
// baseline (340.693 us; speedup 1.0000x reference)
//
#include <hip/hip_runtime.h>
#include <math.h>

#define B 32
#define DA 2
#define DU 1
#define W 64
#define MODES 16
#define L 8192
#define LMASK 8191
#define LT 128   // l-tile per block (combine & lift)

typedef __attribute__((ext_vector_type(8))) short short8;
typedef __attribute__((ext_vector_type(4))) float floatx4;

// ---- workspace layout (32-bit word offsets) ----
// h stored PACKED: uint = (bf16 hi | bf16 lo residual), 17-bit effective precision.
// h layout [b][c][L] (R21: [b][l][c] transpose REFUTED).
#define N_H (B*W*L)                    // 16,777,216 words (64 MB)
#define OFF_H 0
#define N_HF (B*W*MODES)               // 32768
#define OFF_HFR (OFF_H + N_H)
#define OFF_HFI (OFF_HFR + N_HF)       // contiguous with HFR
#define N_GT (B*W*32)                  // 65536 packed g-frag words
#define OFF_GT  (OFF_HFI + N_HF)
#define OFF_BTH (OFF_GT + N_GT)        // combine irfft B hi-plane: L*32 shorts
#define N_BTW (32*L/2)                 // 131072 words
#define OFF_BTL (OFF_BTH + N_BTW)
#define OFF_BFH (OFF_BTL + N_BTW)      // dft B planes: ((s*2+nt)*16+n)*32+(l&31), s=l>>5
#define N_BF (256*2*16*32/2)           // 131072 words
#define OFF_BFL (OFF_BFH + N_BF)
#define OFF_CWH (OFF_BFL + N_BF)       // conv-w frags: 4 layers x 4096 shorts = 8192 words
#define OFF_CWL (OFF_CWH + 8192)
#define OFF_P2  (OFF_CWL + 8192)       // DFT partials: 64 chunks x 65536 fp32 (16 MB)
// total ~ 85 MB (ws ~267 MB)
// PARALLELISM RULE (R10/R12): every kernel needs >=256 blocks.
// STORE RULE (R14 +7.7us): epilogue global stores stream inside the compute loop.
// FUSION RULE (R10/R12/R15): red+mix fusion lost 3x — keep k_red and k_mix separate.
// DIRECT-LOAD (R16, -8us/combine): conv B-fragments load straight from global h
// (coalesced, wave-private l-slice -> in-place h update barrier-free).
// ATOMIC RULE (R17, +145us): cross-XCD f32 atomicAdd into a hot small buffer goes
// memory-side (8 non-coherent L2s) -> ~170MB extra HBM. Spill+reduce is cheaper.
// STALE-BINARY RULE (R18): rename kernels every build (compile cache).
// SPILL RULE (R19/R20): __launch_bounds__ min-waves above natural VGPR fit makes
// the allocator spill to scratch = GLOBAL traffic. VGPR_Count drop vs natural =
// spill signature.
// LAYOUT RULE (R21): [b][l][c] h gave scattered 16B sectors per uint4 instr:
// 46->55us despite 4x fewer VMEM instructions. Segment density > instr count.
// LDS RULE (R22, refuted R8): dft re-read of the just-written 32KB tile from
// global is NOT cache-hot (L1=32KB/CU total; L2 thrash) -> +26MB HBM, 46->51us.
// LDS is the only guaranteed on-chip transpose medium. Keep the swizzled tile.
// 8-WAVE (R23): split the same 128-l tile across 8 waves (512 thr, lt removed):
// per-thread live set halves, occupancy cap 20 -> 32 waves/CU. Same MFMA total,
// bit-identical numerics; dft runs on waves 0-3 as before.

__device__ __forceinline__ unsigned packsplit(float v) {
    unsigned u = __float_as_uint(v);
    unsigned hi = u & 0xffff0000u;
    float lo = v - __uint_as_float(hi);
    return hi | (__float_as_uint(lo) >> 16);
}
__device__ __forceinline__ void fsplit(float v, unsigned short& h, unsigned short& l) {
    unsigned u = __float_as_uint(v);
    h = (unsigned short)(u >> 16);
    float lof = v - __uint_as_float(u & 0xffff0000u);
    l = (unsigned short)(__float_as_uint(lof) >> 16);
}

// merged table build: blocks [0,512) = twiddle tables, [512,576) = conv-w pre-split.
__global__ void k_tables9(short* __restrict__ BTh, short* __restrict__ BTl,
                          short* __restrict__ BFhi, short* __restrict__ BFlo,
                          const float* __restrict__ cw,
                          short* __restrict__ CWFh, short* __restrict__ CWFl) {
    if (blockIdx.x < 512) {
        int idx = blockIdx.x * 256 + threadIdx.x;
        if (idx >= MODES * L) return;
        int k = idx >> 13;
        int l = idx & LMASK;
        int m = (k * l) & LMASK;
        float ang = 6.28318530717958647692f * ((float)m / (float)L);
        float s, c;
        sincosf(ang, &s, &c);
        unsigned short hh, ll;
        fsplit(c, hh, ll);
        BTh[(size_t)l * 32 + k] = (short)hh;  BTl[(size_t)l * 32 + k] = (short)ll;
        int sstep = l >> 5, qj = l & 31;
        int idx_re = ((sstep * 2 + 0) * 16 + k) * 32 + qj;
        BFhi[idx_re] = (short)hh;  BFlo[idx_re] = (short)ll;
        fsplit(s, hh, ll);
        BTh[(size_t)l * 32 + 16 + k] = (short)hh;  BTl[(size_t)l * 32 + 16 + k] = (short)ll;
        unsigned short nh, nl;
        fsplit(-s, nh, nl);
        int idx_im = ((sstep * 2 + 1) * 16 + k) * 32 + qj;
        BFhi[idx_im] = (short)nh;  BFlo[idx_im] = (short)nl;
    } else {
        int idx = (blockIdx.x - 512) * 256 + threadIdx.x;
        if (idx >= 4 * W * W) return;
        int layer = idx >> 12;
        int r = idx & 4095;
        int o = r >> 6, c = r & 63;
        int ot = o >> 4, n = o & 15, Kc = c >> 5, rest = c & 31;
        unsigned short hh, ll;
        fsplit(cw[idx], hh, ll);
        int di = layer * 4096 + ((ot * 2 + Kc) * 16 + n) * 32 + rest;
        CWFh[di] = (short)hh;  CWFl[di] = (short)ll;
    }
}

// ---- fused partial-DFT phase (k_lift / k_combine_emit, threads 0..255) ----
// HsL layout: 64 rows x 128 cols, word col XOR-swizzled by ((c&7)<<2).
__device__ __forceinline__ void dft_partial(const unsigned* HsL,
                                            const short* __restrict__ BFhi,
                                            const short* __restrict__ BFlo,
                                            float* __restrict__ part2,
                                            int b, int l0, int t) {
    int wv = t >> 6, lane = t & 63, quad = lane >> 4, n = lane & 15;
    int sbase = l0 >> 5;
    int c = wv * 16 + n;
    int swz = (c & 7) << 2;
    const unsigned* arow = HsL + c * 128;
    floatx4 accR = {0.f, 0.f, 0.f, 0.f}, accI = {0.f, 0.f, 0.f, 0.f};
#pragma unroll
    for (int ks = 0; ks < 4; ks++) {
        int col = quad * 8 + ks * 32;
        uint4 a0 = *(const uint4*)(arow + (col ^ swz));
        uint4 a1 = *(const uint4*)(arow + ((col + 4) ^ swz));
        unsigned av[8] = {a0.x, a0.y, a0.z, a0.w, a1.x, a1.y, a1.z, a1.w};
        union { short8 v; unsigned short u[8]; } ah, al;
#pragma unroll
        for (int j = 0; j < 8; j++) {
            ah.u[j] = (unsigned short)(av[j] >> 16);
            al.u[j] = (unsigned short)(av[j] & 0xffffu);
        }
        int s = sbase + ks;
        const short* bb = BFhi + ((size_t)(s * 2) * 16 + n) * 32 + quad * 8;
        const short* lb = BFlo + ((size_t)(s * 2) * 16 + n) * 32 + quad * 8;
        short8 BhR = *(const short8*)bb;
        short8 BlR = *(const short8*)lb;
        short8 BhI = *(const short8*)(bb + 512);
        short8 BlI = *(const short8*)(lb + 512);
        accR = __builtin_amdgcn_mfma_f32_16x16x32_bf16(ah.v, BhR, accR, 0, 0, 0);
        accR = __builtin_amdgcn_mfma_f32_16x16x32_bf16(ah.v, BlR, accR, 0, 0, 0);
        accR = __builtin_amdgcn_mfma_f32_16x16x32_bf16(al.v, BhR, accR, 0, 0, 0);
        accI = __builtin_amdgcn_mfma_f32_16x16x32_bf16(ah.v, BhI, accI, 0, 0, 0);
        accI = __builtin_amdgcn_mfma_f32_16x16x32_bf16(ah.v, BlI, accI, 0, 0, 0);
        accI = __builtin_amdgcn_mfma_f32_16x16x32_bf16(al.v, BhI, accI, 0, 0, 0);
    }
    float* pr = part2 + (size_t)(l0 >> 7) * 65536
                      + ((size_t)b * 64 + wv * 16 + quad * 4) * 32 + n;
#pragma unroll
    for (int r = 0; r < 4; r++) {
        pr[(size_t)r * 32]      = accR[r];
        pr[(size_t)r * 32 + 16] = accI[r];
    }
}

// lifting conv -> packed h (uint4-vectorized), fused with partial-DFT of layer 0
__global__ __launch_bounds__(256) void k_lift9(const float* __restrict__ x,
                                               const float* __restrict__ Pw,
                                               const float* __restrict__ Pb,
                                               unsigned* __restrict__ h,
                                               const short* __restrict__ BFhi,
                                               const short* __restrict__ BFlo,
                                               float* __restrict__ part2) {
    __shared__ unsigned HsL[64 * 128];
    int t = threadIdx.x;
    int b = blockIdx.y;
    int l0 = blockIdx.x * LT;
    int lq = t & 31, c8 = t >> 5;                  // thread: 4 consecutive l x 8 c
    float4 x0 = *((const float4*)(x + (size_t)(b * 2 + 0) * L + l0) + lq);
    float4 x1 = *((const float4*)(x + (size_t)(b * 2 + 1) * L + l0) + lq);
#pragma unroll
    for (int cc = 0; cc < 8; cc++) {
        int c = c8 * 8 + cc;
        float w0 = Pw[c * 2 + 0], w1 = Pw[c * 2 + 1], pb = Pb[c];
        uint4 pv;
        pv.x = packsplit(fmaf(w0, x0.x, fmaf(w1, x1.x, pb)));
        pv.y = packsplit(fmaf(w0, x0.y, fmaf(w1, x1.y, pb)));
        pv.z = packsplit(fmaf(w0, x0.z, fmaf(w1, x1.z, pb)));
        pv.w = packsplit(fmaf(w0, x0.w, fmaf(w1, x1.w, pb)));
        *(uint4*)(h + ((size_t)b * W + c) * L + l0 + lq * 4) = pv;
        *(uint4*)&HsL[c * 128 + ((lq * 4) ^ ((c & 7) << 2))] = pv;
    }
    __syncthreads();
    dft_partial(HsL, BFhi, BFlo, part2, b, l0, t);
}

// reduce 64 chunks of part2 -> hf (hfr | hfi contiguous). 256 blocks, coalesced.
__global__ void k_red9(const float* __restrict__ part2, float* __restrict__ hf) {
    int idx = blockIdx.x * 256 + threadIdx.x;      // row*32 + kappa
    float s = 0.f;
#pragma unroll 16
    for (int c = 0; c < 64; c++) s += part2[(size_t)c * 65536 + idx];
    int row = idx >> 5, kp = idx & 31;
    if (kp < 16) hf[row * 16 + kp] = s;
    else         hf[32768 + row * 16 + (kp - 16)] = s;
}

// complex mode mix -> packed fragment-ready Gt (sign + irfft scale folded).
// (16,8) grid — tiny & L3-hot. Do not fuse (R10/12/15).
__global__ __launch_bounds__(256) void k_mix9(const float* __restrict__ hfr,
                                              const float* __restrict__ hfi,
                                              const float* __restrict__ kwr,
                                              const float* __restrict__ kwi,
                                              unsigned* __restrict__ Gt) {
    __shared__ float wrT[64 * 65], wiT[64 * 65];
    int t = threadIdx.x;
    int k = blockIdx.x;
    const float* wr = kwr + k * 4096;
    const float* wi = kwi + k * 4096;
    for (int i = t; i < 4096; i += 256) {
        int o = i >> 6, c = i & 63;
        wrT[c * 65 + o] = wr[i];
        wiT[c * 65 + o] = wi[i];
    }
    __syncthreads();
    int o = t & 63, bq = t >> 6;
    int b = blockIdx.y * 4 + bq;
    float accr = 0.f, acci = 0.f;
#pragma unroll 8
    for (int c = 0; c < W; c++) {
        float hr = hfr[(b * 64 + c) * 16 + k];
        float hi = hfi[(b * 64 + c) * 16 + k];
        float wrv = wrT[c * 65 + o], wiv = wiT[c * 65 + o];
        accr = fmaf(wrv, hr, fmaf(-wiv, hi, accr));
        acci = fmaf(wrv, hi, fmaf(wiv, hr, acci));
    }
    float sc = (k == 0) ? (1.f / (float)L) : (2.f / (float)L);
    float gi = (k == 0) ? 0.f : -acci * sc;
    Gt[((size_t)b * 64 + o) * 32 + k]      = packsplit(accr * sc);
    Gt[((size_t)b * 64 + o) * 32 + 16 + k] = packsplit(gi);
}

// branch-free erf (A&S 7.1.26)
__device__ __forceinline__ float erf_fast(float x) {
    float ax = fabsf(x);
    float tinv = __builtin_amdgcn_rcpf(fmaf(0.3275911f, ax, 1.f));
    float p = fmaf(1.061405429f, tinv, -1.453152027f);
    p = fmaf(p, tinv, 1.421413741f);
    p = fmaf(p, tinv, -0.284496736f);
    p = fmaf(p, tinv, 0.254829592f);
    p = p * tinv;
    float e = fmaf(-p, __expf(-ax * ax), 1.f);
    return copysignf(e, x);
}

// fused combine v17 (R23): 8-wave / 512-thread blocks, lt dimension removed.
// Each wave owns 16 l (lg = l0 + wv*16 + n); per-thread live set halved vs the
// 4-wave form. DIRECT global B-frag loads (R16); swizzled LDS tile for dft (R22).
//  EMIT=1 (layers 0-2): write h + Hs; dft on waves 0-3 after the barrier.
//  PROJ=1 (layer 3):    no h write, no LDS; Q-projection epilogue, barrier-free.
template<int EMIT, int PROJ>
__device__ __forceinline__ void combine_body9(
    unsigned* __restrict__ h, const short* __restrict__ BTh, const short* __restrict__ BTl,
    const unsigned* __restrict__ Gt,
    const short* __restrict__ cwfh, const short* __restrict__ cwfl,
    const float* __restrict__ cb,
    const short* __restrict__ BFhi, const short* __restrict__ BFlo,
    float* __restrict__ part2,
    const float* __restrict__ Qw, const float* __restrict__ Qb,
    float* __restrict__ outbuf,
    unsigned* Hs) {
    int t = threadIdx.x;
    int b = blockIdx.y;
    int l0 = blockIdx.x * LT;

    int lane = t & 63, wv = t >> 6;                // wv 0..7
    int quad = lane >> 4, n = lane & 15;
    int lg = l0 + wv * 16 + n;
    int lloc = wv * 16 + n;

    // B-fragments direct from global h (R16): per load instr each quad's 16
    // n-lanes hit a 64B segment; 8 waves cover the full 128-l tile. Reads and
    // writes of h are wave-private in l -> in-place update barrier-free.
    unsigned rawB[2][8];
    short8 Th, Tl;
    {
        const unsigned* hb = h + (size_t)b * W * L + lg;
#pragma unroll
        for (int Kc = 0; Kc < 2; Kc++) {
#pragma unroll
            for (int j = 0; j < 8; j++) {
                int c = Kc * 32 + quad * 8 + j;
                rawB[Kc][j] = hb[(size_t)c * L];
            }
        }
        Th = *(const short8*)(BTh + (size_t)lg * 32 + quad * 8);
        Tl = *(const short8*)(BTl + (size_t)lg * 32 + quad * 8);
    }
    short8 Bh[2], Bl[2];
#pragma unroll
    for (int Kc = 0; Kc < 2; Kc++) {
        union { short8 v; unsigned short u[8]; } uh, ul;
#pragma unroll
        for (int j = 0; j < 8; j++) {
            unsigned x = rawB[Kc][j];
            uh.u[j] = (unsigned short)(x >> 16);
            ul.u[j] = (unsigned short)(x & 0xffffu);
        }
        Bh[Kc] = uh.v; Bl[Kc] = ul.v;
    }

    float pacc = 0.f;                              // proj partial

#pragma unroll 2
    for (int ot = 0; ot < 4; ot++) {
        int oa = ot * 16 + n;
        short8 Wh[2], Wl[2];
#pragma unroll
        for (int Kc = 0; Kc < 2; Kc++) {
            int wi = ((ot * 2 + Kc) * 16 + n) * 32 + quad * 8;
            Wh[Kc] = *(const short8*)(cwfh + wi);
            Wl[Kc] = *(const short8*)(cwfl + wi);
        }
        short8 Gh, Gl;
        {
            const uint4* gp = (const uint4*)(Gt + ((size_t)b * W + oa) * 32 + quad * 8);
            uint4 g0 = gp[0], g1 = gp[1];
            unsigned gv[8] = {g0.x, g0.y, g0.z, g0.w, g1.x, g1.y, g1.z, g1.w};
            union { short8 v; unsigned short u[8]; } ah, al;
#pragma unroll
            for (int j = 0; j < 8; j++) {
                ah.u[j] = (unsigned short)(gv[j] >> 16);
                al.u[j] = (unsigned short)(gv[j] & 0xffffu);
            }
            Gh = ah.v; Gl = al.v;
        }

        floatx4 acc = {0.f, 0.f, 0.f, 0.f};
#pragma unroll
        for (int Kc = 0; Kc < 2; Kc++) {
            acc = __builtin_amdgcn_mfma_f32_16x16x32_bf16(Wh[Kc], Bh[Kc], acc, 0, 0, 0);
            acc = __builtin_amdgcn_mfma_f32_16x16x32_bf16(Wh[Kc], Bl[Kc], acc, 0, 0, 0);
            acc = __builtin_amdgcn_mfma_f32_16x16x32_bf16(Wl[Kc], Bh[Kc], acc, 0, 0, 0);
        }
        acc = __builtin_amdgcn_mfma_f32_16x16x32_bf16(Gh, Th, acc, 0, 0, 0);
        acc = __builtin_amdgcn_mfma_f32_16x16x32_bf16(Gh, Tl, acc, 0, 0, 0);
        acc = __builtin_amdgcn_mfma_f32_16x16x32_bf16(Gl, Th, acc, 0, 0, 0);
#pragma unroll
        for (int r = 0; r < 4; r++) {
            int od = ot * 16 + quad * 4 + r;
            float v = acc[r] + cb[od];
            float g = 0.5f * v * (1.f + erf_fast(v * 0.70710678118654752440f));
            if (PROJ) {
                pacc = fmaf(Qw[od], g, pacc);
            } else {
                unsigned p = packsplit(g);
                h[((size_t)b * W + od) * L + lg] = p;
                if (EMIT) Hs[od * 128 + (lloc ^ ((od & 7) << 2))] = p;
            }
        }
    }
    if (EMIT) {
        __syncthreads();
        if (t < 256) dft_partial(Hs, BFhi, BFlo, part2, b, l0, t);
    }
    if (PROJ) {
        float v = pacc;
        v += __shfl_xor(v, 16, 64);                // sum quad pairs
        v += __shfl_xor(v, 32, 64);                // sum all 4 quads
        if (quad == 0)
            outbuf[(size_t)b * L + lg] = v + Qb[0];
    }
}

__global__ __launch_bounds__(512, 4) void k_combine_emit9(
    unsigned* __restrict__ h, const short* __restrict__ BTh, const short* __restrict__ BTl,
    const unsigned* __restrict__ Gt,
    const short* __restrict__ cwfh, const short* __restrict__ cwfl,
    const float* __restrict__ cb,
    const short* __restrict__ BFhi, const short* __restrict__ BFlo,
    float* __restrict__ part2) {
    __shared__ unsigned Hs[64 * 128];
    combine_body9<1, 0>(h, BTh, BTl, Gt, cwfh, cwfl, cb, BFhi, BFlo, part2,
                        nullptr, nullptr, nullptr, Hs);
}

__global__ __launch_bounds__(512, 4) void k_combine_proj9(
    unsigned* __restrict__ h, const short* __restrict__ BTh, const short* __restrict__ BTl,
    const unsigned* __restrict__ Gt,
    const short* __restrict__ cwfh, const short* __restrict__ cwfl,
    const float* __restrict__ cb,
    const float* __restrict__ Qw, const float* __restrict__ Qb,
    float* __restrict__ outbuf) {
    combine_body9<0, 1>(h, BTh, BTl, Gt, cwfh, cwfl, cb, nullptr, nullptr, nullptr,
                        Qw, Qb, outbuf, nullptr);
}

extern "C" void kernel_launch(void* const* d_in, const int* in_sizes, int n_in,
                              void* d_out, int out_size, void* d_ws, size_t ws_size,
                              hipStream_t stream) {
    const float* x   = (const float*)d_in[0];
    const float* Pw  = (const float*)d_in[1];
    const float* Pb  = (const float*)d_in[2];
    const float* kwr = (const float*)d_in[3];
    const float* kwi = (const float*)d_in[4];
    const float* cw  = (const float*)d_in[5];
    const float* cb  = (const float*)d_in[6];
    const float* Qw  = (const float*)d_in[7];
    const float* Qb  = (const float*)d_in[8];

    float* ws = (float*)d_ws;
    unsigned* h    = (unsigned*)(ws + OFF_H);
    float*    hfr  = ws + OFF_HFR;
    float*    hfi  = ws + OFF_HFI;
    unsigned* Gt   = (unsigned*)(ws + OFF_GT);
    short*    BTh  = (short*)(ws + OFF_BTH);
    short*    BTl  = (short*)(ws + OFF_BTL);
    short*    BFhi = (short*)(ws + OFF_BFH);
    short*    BFlo = (short*)(ws + OFF_BFL);
    short*    CWFh = (short*)(ws + OFF_CWH);
    short*    CWFl = (short*)(ws + OFF_CWL);
    float*    part2 = ws + OFF_P2;

    k_tables9<<<512 + 64, 256, 0, stream>>>(BTh, BTl, BFhi, BFlo, cw, CWFh, CWFl);
    k_lift9<<<dim3(L / LT, B), 256, 0, stream>>>(x, Pw, Pb, h, BFhi, BFlo, part2);

    for (int i = 0; i < 4; i++) {
        k_red9<<<65536 / 256, 256, 0, stream>>>(part2, hfr);
        k_mix9<<<dim3(MODES, B / 4), 256, 0, stream>>>(hfr, hfi,
                                                       kwr + (size_t)i * MODES * W * W,
                                                       kwi + (size_t)i * MODES * W * W,
                                                       Gt);
        if (i < 3) {
            k_combine_emit9<<<dim3(L / LT, B), 512, 0, stream>>>(h, BTh, BTl, Gt,
                                                                 CWFh + (size_t)i * 4096,
                                                                 CWFl + (size_t)i * 4096,
                                                                 cb + (size_t)i * W,
                                                                 BFhi, BFlo, part2);
        } else {
            k_combine_proj9<<<dim3(L / LT, B), 512, 0, stream>>>(h, BTh, BTl, Gt,
                                                                 CWFh + (size_t)i * 4096,
                                                                 CWFl + (size_t)i * 4096,
                                                                 cb + (size_t)i * W,
                                                                 Qw, Qb, (float*)d_out);
        }
    }
}

// Round 10
// 297.840 us; speedup vs baseline: 1.1439x; 1.1439x over previous
//
#include <hip/hip_runtime.h>
#include <math.h>

#define B 32
#define DA 2
#define DU 1
#define W 64
#define MODES 16
#define L 8192
#define LMASK 8191
#define LT 128   // l-tile per block (combine & lift)

typedef __attribute__((ext_vector_type(8))) short short8;
typedef __attribute__((ext_vector_type(4))) float floatx4;

// ---- workspace layout (32-bit word offsets) ----
// h stored PACKED: uint = (bf16 hi | bf16 lo residual), 17-bit effective precision.
// h layout [b][c][L] (R21: [b][l][c] transpose REFUTED).
#define N_H (B*W*L)                    // 16,777,216 words (64 MB)
#define OFF_H 0
#define N_HF (B*W*MODES)               // 32768
#define OFF_HFR (OFF_H + N_H)
#define OFF_HFI (OFF_HFR + N_HF)       // contiguous with HFR
#define N_GT (B*W*32)                  // 65536 packed g-frag words
#define OFF_GT  (OFF_HFI + N_HF)
#define OFF_BTH (OFF_GT + N_GT)        // combine irfft B hi-plane: L*32 shorts
#define N_BTW (32*L/2)                 // 131072 words
#define OFF_BTL (OFF_BTH + N_BTW)
#define OFF_BFH (OFF_BTL + N_BTW)      // dft B planes: ((s*2+nt)*16+n)*32+(l&31), s=l>>5
#define N_BF (256*2*16*32/2)           // 131072 words
#define OFF_BFL (OFF_BFH + N_BF)
#define OFF_CWH (OFF_BFL + N_BF)       // conv-w frags: 4 layers x 4096 shorts = 8192 words
#define OFF_CWL (OFF_CWH + 8192)
#define OFF_P2  (OFF_CWL + 8192)       // DFT partials: 64 chunks x 65536 fp32 (16 MB)
// total ~ 85 MB (ws ~267 MB)
// PARALLELISM RULE (R10/R12): every kernel needs >=256 blocks.
// STORE RULE (R14 +7.7us): epilogue global stores stream inside the compute loop.
// FUSION RULE (R10/R12/R15): red+mix fusion lost 3x — keep k_red and k_mix separate.
// DIRECT-LOAD (R16, -8us/combine): conv B-fragments load straight from global h
// (coalesced, wave-private l-slice -> in-place h update barrier-free).
// ATOMIC RULE (R17, +145us): cross-XCD f32 atomicAdd into a hot small buffer goes
// memory-side (8 non-coherent L2s) -> ~170MB extra HBM. Spill+reduce is cheaper.
// STALE-BINARY RULE (R18): rename kernels every build (compile cache).
// SPILL RULE (R19/R20): __launch_bounds__ min-waves above natural VGPR fit makes
// the allocator spill to scratch = GLOBAL traffic. VGPR_Count drop vs natural =
// spill signature. Use (256,4).
// LAYOUT RULE (R21): [b][l][c] h gave scattered 16B sectors per uint4 instr:
// 46->55us despite 4x fewer VMEM instructions. Segment density > instr count.
// LDS RULE (R22, refuted R8): dft re-read of the just-written 32KB tile from
// global is NOT cache-hot (+26MB HBM, 46->51us). LDS is the only guaranteed
// on-chip transpose medium. Keep the swizzled tile.
// TLP RULE (R23, refuted R9): achieved occupancy (36%) is INVARIANT under cap
// changes (R8 LDS=0, R9 8-wave 100% cap) -> latency floor is structural (grid
// tail at 8 blocks/CU of work + barrier drains), not resource-capped. Do not
// chase occupancy further.
// NT-PART2 (R24): part2 is a write-once/read-once/dead 16MB stream per layer;
// mark it non-temporal so it stops churning L3 and evicting h (emit FETCH 36MB
// despite an 80MB working set in 256MB L3).

__device__ __forceinline__ unsigned packsplit(float v) {
    unsigned u = __float_as_uint(v);
    unsigned hi = u & 0xffff0000u;
    float lo = v - __uint_as_float(hi);
    return hi | (__float_as_uint(lo) >> 16);
}
__device__ __forceinline__ void fsplit(float v, unsigned short& h, unsigned short& l) {
    unsigned u = __float_as_uint(v);
    h = (unsigned short)(u >> 16);
    float lof = v - __uint_as_float(u & 0xffff0000u);
    l = (unsigned short)(__float_as_uint(lof) >> 16);
}

// merged table build: blocks [0,512) = twiddle tables, [512,576) = conv-w pre-split.
__global__ void k_tables10(short* __restrict__ BTh, short* __restrict__ BTl,
                           short* __restrict__ BFhi, short* __restrict__ BFlo,
                           const float* __restrict__ cw,
                           short* __restrict__ CWFh, short* __restrict__ CWFl) {
    if (blockIdx.x < 512) {
        int idx = blockIdx.x * 256 + threadIdx.x;
        if (idx >= MODES * L) return;
        int k = idx >> 13;
        int l = idx & LMASK;
        int m = (k * l) & LMASK;
        float ang = 6.28318530717958647692f * ((float)m / (float)L);
        float s, c;
        sincosf(ang, &s, &c);
        unsigned short hh, ll;
        fsplit(c, hh, ll);
        BTh[(size_t)l * 32 + k] = (short)hh;  BTl[(size_t)l * 32 + k] = (short)ll;
        int sstep = l >> 5, qj = l & 31;
        int idx_re = ((sstep * 2 + 0) * 16 + k) * 32 + qj;
        BFhi[idx_re] = (short)hh;  BFlo[idx_re] = (short)ll;
        fsplit(s, hh, ll);
        BTh[(size_t)l * 32 + 16 + k] = (short)hh;  BTl[(size_t)l * 32 + 16 + k] = (short)ll;
        unsigned short nh, nl;
        fsplit(-s, nh, nl);
        int idx_im = ((sstep * 2 + 1) * 16 + k) * 32 + qj;
        BFhi[idx_im] = (short)nh;  BFlo[idx_im] = (short)nl;
    } else {
        int idx = (blockIdx.x - 512) * 256 + threadIdx.x;
        if (idx >= 4 * W * W) return;
        int layer = idx >> 12;
        int r = idx & 4095;
        int o = r >> 6, c = r & 63;
        int ot = o >> 4, n = o & 15, Kc = c >> 5, rest = c & 31;
        unsigned short hh, ll;
        fsplit(cw[idx], hh, ll);
        int di = layer * 4096 + ((ot * 2 + Kc) * 16 + n) * 32 + rest;
        CWFh[di] = (short)hh;  CWFl[di] = (short)ll;
    }
}

// ---- fused partial-DFT phase (shared by k_lift / k_combine_emit) ----
// HsL layout: 64 rows x 128 cols, word col XOR-swizzled by ((c&7)<<2).
// part2 stores are NON-TEMPORAL (R24): write-once stream, keep L3 for h.
__device__ __forceinline__ void dft_partial(const unsigned* HsL,
                                            const short* __restrict__ BFhi,
                                            const short* __restrict__ BFlo,
                                            float* __restrict__ part2,
                                            int b, int l0, int t) {
    int wv = t >> 6, lane = t & 63, quad = lane >> 4, n = lane & 15;
    int sbase = l0 >> 5;
    int c = wv * 16 + n;
    int swz = (c & 7) << 2;
    const unsigned* arow = HsL + c * 128;
    floatx4 accR = {0.f, 0.f, 0.f, 0.f}, accI = {0.f, 0.f, 0.f, 0.f};
#pragma unroll
    for (int ks = 0; ks < 4; ks++) {
        int col = quad * 8 + ks * 32;
        uint4 a0 = *(const uint4*)(arow + (col ^ swz));
        uint4 a1 = *(const uint4*)(arow + ((col + 4) ^ swz));
        unsigned av[8] = {a0.x, a0.y, a0.z, a0.w, a1.x, a1.y, a1.z, a1.w};
        union { short8 v; unsigned short u[8]; } ah, al;
#pragma unroll
        for (int j = 0; j < 8; j++) {
            ah.u[j] = (unsigned short)(av[j] >> 16);
            al.u[j] = (unsigned short)(av[j] & 0xffffu);
        }
        int s = sbase + ks;
        const short* bb = BFhi + ((size_t)(s * 2) * 16 + n) * 32 + quad * 8;
        const short* lb = BFlo + ((size_t)(s * 2) * 16 + n) * 32 + quad * 8;
        short8 BhR = *(const short8*)bb;
        short8 BlR = *(const short8*)lb;
        short8 BhI = *(const short8*)(bb + 512);
        short8 BlI = *(const short8*)(lb + 512);
        accR = __builtin_amdgcn_mfma_f32_16x16x32_bf16(ah.v, BhR, accR, 0, 0, 0);
        accR = __builtin_amdgcn_mfma_f32_16x16x32_bf16(ah.v, BlR, accR, 0, 0, 0);
        accR = __builtin_amdgcn_mfma_f32_16x16x32_bf16(al.v, BhR, accR, 0, 0, 0);
        accI = __builtin_amdgcn_mfma_f32_16x16x32_bf16(ah.v, BhI, accI, 0, 0, 0);
        accI = __builtin_amdgcn_mfma_f32_16x16x32_bf16(ah.v, BlI, accI, 0, 0, 0);
        accI = __builtin_amdgcn_mfma_f32_16x16x32_bf16(al.v, BhI, accI, 0, 0, 0);
    }
    float* pr = part2 + (size_t)(l0 >> 7) * 65536
                      + ((size_t)b * 64 + wv * 16 + quad * 4) * 32 + n;
#pragma unroll
    for (int r = 0; r < 4; r++) {
        __builtin_nontemporal_store(accR[r], pr + (size_t)r * 32);
        __builtin_nontemporal_store(accI[r], pr + (size_t)r * 32 + 16);
    }
}

// lifting conv -> packed h (uint4-vectorized), fused with partial-DFT of layer 0
__global__ __launch_bounds__(256) void k_lift10(const float* __restrict__ x,
                                                const float* __restrict__ Pw,
                                                const float* __restrict__ Pb,
                                                unsigned* __restrict__ h,
                                                const short* __restrict__ BFhi,
                                                const short* __restrict__ BFlo,
                                                float* __restrict__ part2) {
    __shared__ unsigned HsL[64 * 128];
    int t = threadIdx.x;
    int b = blockIdx.y;
    int l0 = blockIdx.x * LT;
    int lq = t & 31, c8 = t >> 5;                  // thread: 4 consecutive l x 8 c
    float4 x0 = *((const float4*)(x + (size_t)(b * 2 + 0) * L + l0) + lq);
    float4 x1 = *((const float4*)(x + (size_t)(b * 2 + 1) * L + l0) + lq);
#pragma unroll
    for (int cc = 0; cc < 8; cc++) {
        int c = c8 * 8 + cc;
        float w0 = Pw[c * 2 + 0], w1 = Pw[c * 2 + 1], pb = Pb[c];
        uint4 pv;
        pv.x = packsplit(fmaf(w0, x0.x, fmaf(w1, x1.x, pb)));
        pv.y = packsplit(fmaf(w0, x0.y, fmaf(w1, x1.y, pb)));
        pv.z = packsplit(fmaf(w0, x0.z, fmaf(w1, x1.z, pb)));
        pv.w = packsplit(fmaf(w0, x0.w, fmaf(w1, x1.w, pb)));
        *(uint4*)(h + ((size_t)b * W + c) * L + l0 + lq * 4) = pv;
        *(uint4*)&HsL[c * 128 + ((lq * 4) ^ ((c & 7) << 2))] = pv;
    }
    __syncthreads();
    dft_partial(HsL, BFhi, BFlo, part2, b, l0, t);
}

// reduce 64 chunks of part2 -> hf (hfr | hfi contiguous). 256 blocks, coalesced.
// Non-temporal part2 reads (R24): read-once stream, dead after this.
__global__ void k_red10(const float* __restrict__ part2, float* __restrict__ hf) {
    int idx = blockIdx.x * 256 + threadIdx.x;      // row*32 + kappa
    float s = 0.f;
#pragma unroll 16
    for (int c = 0; c < 64; c++)
        s += __builtin_nontemporal_load(part2 + (size_t)c * 65536 + idx);
    int row = idx >> 5, kp = idx & 31;
    if (kp < 16) hf[row * 16 + kp] = s;
    else         hf[32768 + row * 16 + (kp - 16)] = s;
}

// complex mode mix -> packed fragment-ready Gt (sign + irfft scale folded).
// (16,8) grid — tiny & L3-hot. Do not fuse (R10/12/15).
__global__ __launch_bounds__(256) void k_mix10(const float* __restrict__ hfr,
                                               const float* __restrict__ hfi,
                                               const float* __restrict__ kwr,
                                               const float* __restrict__ kwi,
                                               unsigned* __restrict__ Gt) {
    __shared__ float wrT[64 * 65], wiT[64 * 65];
    int t = threadIdx.x;
    int k = blockIdx.x;
    const float* wr = kwr + k * 4096;
    const float* wi = kwi + k * 4096;
    for (int i = t; i < 4096; i += 256) {
        int o = i >> 6, c = i & 63;
        wrT[c * 65 + o] = wr[i];
        wiT[c * 65 + o] = wi[i];
    }
    __syncthreads();
    int o = t & 63, bq = t >> 6;
    int b = blockIdx.y * 4 + bq;
    float accr = 0.f, acci = 0.f;
#pragma unroll 8
    for (int c = 0; c < W; c++) {
        float hr = hfr[(b * 64 + c) * 16 + k];
        float hi = hfi[(b * 64 + c) * 16 + k];
        float wrv = wrT[c * 65 + o], wiv = wiT[c * 65 + o];
        accr = fmaf(wrv, hr, fmaf(-wiv, hi, accr));
        acci = fmaf(wrv, hi, fmaf(wiv, hr, acci));
    }
    float sc = (k == 0) ? (1.f / (float)L) : (2.f / (float)L);
    float gi = (k == 0) ? 0.f : -acci * sc;
    Gt[((size_t)b * 64 + o) * 32 + k]      = packsplit(accr * sc);
    Gt[((size_t)b * 64 + o) * 32 + 16 + k] = packsplit(gi);
}

// branch-free erf (A&S 7.1.26)
__device__ __forceinline__ float erf_fast(float x) {
    float ax = fabsf(x);
    float tinv = __builtin_amdgcn_rcpf(fmaf(0.3275911f, ax, 1.f));
    float p = fmaf(1.061405429f, tinv, -1.453152027f);
    p = fmaf(p, tinv, 1.421413741f);
    p = fmaf(p, tinv, -0.284496736f);
    p = fmaf(p, tinv, 0.254829592f);
    p = p * tinv;
    float e = fmaf(-p, __expf(-ax * ax), 1.f);
    return copysignf(e, x);
}

// fused combine v18 (R24 = R6 structure + nt part2): conv + irfft + gelu (MFMA
// split-bf16), DIRECT global B-fragment loads; stores stream in the compute loop.
//  EMIT=1 (layers 0-2): write h + Hs; dft (nt part2 stores) after the barrier.
//  PROJ=1 (layer 3):    no h write, no LDS; Q-projection epilogue, barrier-free.
template<int EMIT, int PROJ>
__device__ __forceinline__ void combine_body(
    unsigned* __restrict__ h, const short* __restrict__ BTh, const short* __restrict__ BTl,
    const unsigned* __restrict__ Gt,
    const short* __restrict__ cwfh, const short* __restrict__ cwfl,
    const float* __restrict__ cb,
    const short* __restrict__ BFhi, const short* __restrict__ BFlo,
    float* __restrict__ part2,
    const float* __restrict__ Qw, const float* __restrict__ Qb,
    float* __restrict__ outbuf,
    unsigned* Hs) {
    int t = threadIdx.x;
    int b = blockIdx.y;
    int l0 = blockIdx.x * LT;

    int lane = t & 63, wv = t >> 6;
    int quad = lane >> 4, n = lane & 15;

    // B-fragments direct from global h (R16): 64B segments, lt pair covers full
    // 128B lines; wave-private l-slice -> in-place h update barrier-free.
    unsigned rawB[2][2][8];
    short8 Th[2], Tl[2];
#pragma unroll
    for (int lt = 0; lt < 2; lt++) {
        int lg = l0 + wv * 32 + lt * 16 + n;
        const unsigned* hb = h + (size_t)b * W * L + lg;
#pragma unroll
        for (int Kc = 0; Kc < 2; Kc++) {
#pragma unroll
            for (int j = 0; j < 8; j++) {
                int c = Kc * 32 + quad * 8 + j;
                rawB[lt][Kc][j] = hb[(size_t)c * L];
            }
        }
        Th[lt] = *(const short8*)(BTh + (size_t)lg * 32 + quad * 8);
        Tl[lt] = *(const short8*)(BTl + (size_t)lg * 32 + quad * 8);
    }
    short8 Bh[2][2], Bl[2][2];
#pragma unroll
    for (int lt = 0; lt < 2; lt++) {
#pragma unroll
        for (int Kc = 0; Kc < 2; Kc++) {
            union { short8 v; unsigned short u[8]; } uh, ul;
#pragma unroll
            for (int j = 0; j < 8; j++) {
                unsigned x = rawB[lt][Kc][j];
                uh.u[j] = (unsigned short)(x >> 16);
                ul.u[j] = (unsigned short)(x & 0xffffu);
            }
            Bh[lt][Kc] = uh.v; Bl[lt][Kc] = ul.v;
        }
    }

    float pacc[2] = {0.f, 0.f};                    // proj partials per lt

#pragma unroll 2
    for (int ot = 0; ot < 4; ot++) {
        int oa = ot * 16 + n;
        short8 Wh[2], Wl[2];
#pragma unroll
        for (int Kc = 0; Kc < 2; Kc++) {
            int wi = ((ot * 2 + Kc) * 16 + n) * 32 + quad * 8;
            Wh[Kc] = *(const short8*)(cwfh + wi);
            Wl[Kc] = *(const short8*)(cwfl + wi);
        }
        short8 Gh, Gl;
        {
            const uint4* gp = (const uint4*)(Gt + ((size_t)b * W + oa) * 32 + quad * 8);
            uint4 g0 = gp[0], g1 = gp[1];
            unsigned gv[8] = {g0.x, g0.y, g0.z, g0.w, g1.x, g1.y, g1.z, g1.w};
            union { short8 v; unsigned short u[8]; } ah, al;
#pragma unroll
            for (int j = 0; j < 8; j++) {
                ah.u[j] = (unsigned short)(gv[j] >> 16);
                al.u[j] = (unsigned short)(gv[j] & 0xffffu);
            }
            Gh = ah.v; Gl = al.v;
        }

#pragma unroll
        for (int lt = 0; lt < 2; lt++) {
            floatx4 acc = {0.f, 0.f, 0.f, 0.f};
#pragma unroll
            for (int Kc = 0; Kc < 2; Kc++) {
                acc = __builtin_amdgcn_mfma_f32_16x16x32_bf16(Wh[Kc], Bh[lt][Kc], acc, 0, 0, 0);
                acc = __builtin_amdgcn_mfma_f32_16x16x32_bf16(Wh[Kc], Bl[lt][Kc], acc, 0, 0, 0);
                acc = __builtin_amdgcn_mfma_f32_16x16x32_bf16(Wl[Kc], Bh[lt][Kc], acc, 0, 0, 0);
            }
            acc = __builtin_amdgcn_mfma_f32_16x16x32_bf16(Gh, Th[lt], acc, 0, 0, 0);
            acc = __builtin_amdgcn_mfma_f32_16x16x32_bf16(Gh, Tl[lt], acc, 0, 0, 0);
            acc = __builtin_amdgcn_mfma_f32_16x16x32_bf16(Gl, Th[lt], acc, 0, 0, 0);
            int lloc = wv * 32 + lt * 16 + n;
            int lg = l0 + lloc;
#pragma unroll
            for (int r = 0; r < 4; r++) {
                int od = ot * 16 + quad * 4 + r;
                float v = acc[r] + cb[od];
                float g = 0.5f * v * (1.f + erf_fast(v * 0.70710678118654752440f));
                if (PROJ) {
                    pacc[lt] = fmaf(Qw[od], g, pacc[lt]);
                } else {
                    unsigned p = packsplit(g);
                    h[((size_t)b * W + od) * L + lg] = p;
                    if (EMIT) Hs[od * 128 + (lloc ^ ((od & 7) << 2))] = p;
                }
            }
        }
    }
    if (EMIT) {
        __syncthreads();
        dft_partial(Hs, BFhi, BFlo, part2, b, l0, t);
    }
    if (PROJ) {
        float qb = Qb[0];
#pragma unroll
        for (int lt = 0; lt < 2; lt++) {
            float v = pacc[lt];
            v += __shfl_xor(v, 16, 64);            // sum quad pairs
            v += __shfl_xor(v, 32, 64);            // sum all 4 quads
            if (quad == 0)
                __builtin_nontemporal_store(v + qb,
                    outbuf + (size_t)b * L + l0 + wv * 32 + lt * 16 + n);
        }
    }
}

__global__ __launch_bounds__(256, 4) void k_combine_emit10(
    unsigned* __restrict__ h, const short* __restrict__ BTh, const short* __restrict__ BTl,
    const unsigned* __restrict__ Gt,
    const short* __restrict__ cwfh, const short* __restrict__ cwfl,
    const float* __restrict__ cb,
    const short* __restrict__ BFhi, const short* __restrict__ BFlo,
    float* __restrict__ part2) {
    __shared__ unsigned Hs[64 * 128];
    combine_body<1, 0>(h, BTh, BTl, Gt, cwfh, cwfl, cb, BFhi, BFlo, part2,
                       nullptr, nullptr, nullptr, Hs);
}

__global__ __launch_bounds__(256, 4) void k_combine_proj10(
    unsigned* __restrict__ h, const short* __restrict__ BTh, const short* __restrict__ BTl,
    const unsigned* __restrict__ Gt,
    const short* __restrict__ cwfh, const short* __restrict__ cwfl,
    const float* __restrict__ cb,
    const float* __restrict__ Qw, const float* __restrict__ Qb,
    float* __restrict__ outbuf) {
    combine_body<0, 1>(h, BTh, BTl, Gt, cwfh, cwfl, cb, nullptr, nullptr, nullptr,
                       Qw, Qb, outbuf, nullptr);
}

extern "C" void kernel_launch(void* const* d_in, const int* in_sizes, int n_in,
                              void* d_out, int out_size, void* d_ws, size_t ws_size,
                              hipStream_t stream) {
    const float* x   = (const float*)d_in[0];
    const float* Pw  = (const float*)d_in[1];
    const float* Pb  = (const float*)d_in[2];
    const float* kwr = (const float*)d_in[3];
    const float* kwi = (const float*)d_in[4];
    const float* cw  = (const float*)d_in[5];
    const float* cb  = (const float*)d_in[6];
    const float* Qw  = (const float*)d_in[7];
    const float* Qb  = (const float*)d_in[8];

    float* ws = (float*)d_ws;
    unsigned* h    = (unsigned*)(ws + OFF_H);
    float*    hfr  = ws + OFF_HFR;
    float*    hfi  = ws + OFF_HFI;
    unsigned* Gt   = (unsigned*)(ws + OFF_GT);
    short*    BTh  = (short*)(ws + OFF_BTH);
    short*    BTl  = (short*)(ws + OFF_BTL);
    short*    BFhi = (short*)(ws + OFF_BFH);
    short*    BFlo = (short*)(ws + OFF_BFL);
    short*    CWFh = (short*)(ws + OFF_CWH);
    short*    CWFl = (short*)(ws + OFF_CWL);
    float*    part2 = ws + OFF_P2;

    k_tables10<<<512 + 64, 256, 0, stream>>>(BTh, BTl, BFhi, BFlo, cw, CWFh, CWFl);
    k_lift10<<<dim3(L / LT, B), 256, 0, stream>>>(x, Pw, Pb, h, BFhi, BFlo, part2);

    for (int i = 0; i < 4; i++) {
        k_red10<<<65536 / 256, 256, 0, stream>>>(part2, hfr);
        k_mix10<<<dim3(MODES, B / 4), 256, 0, stream>>>(hfr, hfi,
                                                        kwr + (size_t)i * MODES * W * W,
                                                        kwi + (size_t)i * MODES * W * W,
                                                        Gt);
        if (i < 3) {
            k_combine_emit10<<<dim3(L / LT, B), 256, 0, stream>>>(h, BTh, BTl, Gt,
                                                                  CWFh + (size_t)i * 4096,
                                                                  CWFl + (size_t)i * 4096,
                                                                  cb + (size_t)i * W,
                                                                  BFhi, BFlo, part2);
        } else {
            k_combine_proj10<<<dim3(L / LT, B), 256, 0, stream>>>(h, BTh, BTl, Gt,
                                                                  CWFh + (size_t)i * 4096,
                                                                  CWFl + (size_t)i * 4096,
                                                                  cb + (size_t)i * W,
                                                                  Qw, Qb, (float*)d_out);
        }
    }
}

// Round 11
// 293.056 us; speedup vs baseline: 1.1626x; 1.0163x over previous
//
#include <hip/hip_runtime.h>
#include <math.h>

#define B 32
#define DA 2
#define DU 1
#define W 64
#define MODES 16
#define L 8192
#define LMASK 8191
#define LT 128   // l-tile per block (combine & lift)

typedef __attribute__((ext_vector_type(8))) short short8;
typedef __attribute__((ext_vector_type(4))) float floatx4;

// ---- workspace layout (32-bit word offsets) ----
// h stored PACKED: uint = (bf16 hi | bf16 lo residual), 17-bit effective precision.
// h layout [b][c][L] (R21: [b][l][c] transpose REFUTED).
#define N_H (B*W*L)                    // 16,777,216 words (64 MB)
#define OFF_H 0
#define N_HF (B*W*MODES)               // 32768
#define OFF_HFR (OFF_H + N_H)
#define OFF_HFI (OFF_HFR + N_HF)       // contiguous with HFR
#define N_GT (B*W*32)                  // 65536 packed g-frag words
#define OFF_GT  (OFF_HFI + N_HF)
#define OFF_BTH (OFF_GT + N_GT)        // combine irfft B hi-plane: L*32 shorts
#define N_BTW (32*L/2)                 // 131072 words
#define OFF_BTL (OFF_BTH + N_BTW)
#define OFF_BFH (OFF_BTL + N_BTW)      // dft B planes: ((s*2+nt)*16+n)*32+(l&31), s=l>>5
#define N_BF (256*2*16*32/2)           // 131072 words
#define OFF_BFL (OFF_BFH + N_BF)
#define OFF_CWH (OFF_BFL + N_BF)       // conv-w frags: 4 layers x 4096 shorts = 8192 words
#define OFF_CWL (OFF_CWH + 8192)
#define OFF_P2  (OFF_CWL + 8192)       // DFT partials: 64 chunks x 65536 fp32 (16 MB)
// total ~ 85 MB (ws ~267 MB)
// ===================== RULE LEDGER (all counter-verified) =====================
// PARALLELISM RULE (R10/R12): every kernel needs >=256 blocks.
// STORE RULE (R14 +7.7us): epilogue global stores stream inside the compute loop.
// FUSION RULE (R10/R12/R15): red+mix fusion lost 3x — keep k_red and k_mix separate.
// DIRECT-LOAD (R16, -8us/combine): conv B-fragments load straight from global h
// (coalesced, wave-private l-slice -> in-place h update barrier-free).
// ATOMIC RULE (R17, +145us): cross-XCD f32 atomicAdd into a hot small buffer goes
// memory-side (8 non-coherent L2s) -> ~170MB extra HBM. Spill+reduce is cheaper.
// STALE-BINARY RULE (R18): rename kernels every build (compile cache).
// SPILL RULE (R19/R20): __launch_bounds__ min-waves above natural VGPR fit makes
// the allocator spill to scratch = GLOBAL traffic. Use (256,4); VGPR_Count drop
// vs natural = spill signature.
// LAYOUT RULE (R21): [b][l][c] h gave scattered 16B sectors per uint4 instr:
// 46->55us despite 4x fewer VMEM instructions. Segment density > instr count.
// LDS RULE (R22): dft re-read of the just-written 32KB tile from global is NOT
// cache-hot (+26MB HBM, 46->51us). LDS is the only guaranteed transpose medium.
// TLP RULE (R23): achieved occupancy (36%) is INVARIANT under cap changes (R8
// LDS=0, R9 8-wave 100% cap) -> floor is structural, not resource-capped.
// NT RULE (R24): nontemporal part2 didn't cut h FETCH (36MB unchanged) and
// perturbed codegen (+4 VGPR, +6us). h misses are not part2-eviction-driven.
// PLATEAU: R6 structure = 291.7us. Traffic at algorithmic minimum; no pipe >40%;
// occupancy cap-invariant. Residual = dependent-dispatch latency + barrier drain.
// =============================================================================

__device__ __forceinline__ unsigned packsplit(float v) {
    unsigned u = __float_as_uint(v);
    unsigned hi = u & 0xffff0000u;
    float lo = v - __uint_as_float(hi);
    return hi | (__float_as_uint(lo) >> 16);
}
__device__ __forceinline__ void fsplit(float v, unsigned short& h, unsigned short& l) {
    unsigned u = __float_as_uint(v);
    h = (unsigned short)(u >> 16);
    float lof = v - __uint_as_float(u & 0xffff0000u);
    l = (unsigned short)(__float_as_uint(lof) >> 16);
}

// merged table build: blocks [0,512) = twiddle tables, [512,576) = conv-w pre-split.
__global__ void k_tables11(short* __restrict__ BTh, short* __restrict__ BTl,
                           short* __restrict__ BFhi, short* __restrict__ BFlo,
                           const float* __restrict__ cw,
                           short* __restrict__ CWFh, short* __restrict__ CWFl) {
    if (blockIdx.x < 512) {
        int idx = blockIdx.x * 256 + threadIdx.x;
        if (idx >= MODES * L) return;
        int k = idx >> 13;
        int l = idx & LMASK;
        int m = (k * l) & LMASK;
        float ang = 6.28318530717958647692f * ((float)m / (float)L);
        float s, c;
        sincosf(ang, &s, &c);
        unsigned short hh, ll;
        fsplit(c, hh, ll);
        BTh[(size_t)l * 32 + k] = (short)hh;  BTl[(size_t)l * 32 + k] = (short)ll;
        int sstep = l >> 5, qj = l & 31;
        int idx_re = ((sstep * 2 + 0) * 16 + k) * 32 + qj;
        BFhi[idx_re] = (short)hh;  BFlo[idx_re] = (short)ll;
        fsplit(s, hh, ll);
        BTh[(size_t)l * 32 + 16 + k] = (short)hh;  BTl[(size_t)l * 32 + 16 + k] = (short)ll;
        unsigned short nh, nl;
        fsplit(-s, nh, nl);
        int idx_im = ((sstep * 2 + 1) * 16 + k) * 32 + qj;
        BFhi[idx_im] = (short)nh;  BFlo[idx_im] = (short)nl;
    } else {
        int idx = (blockIdx.x - 512) * 256 + threadIdx.x;
        if (idx >= 4 * W * W) return;
        int layer = idx >> 12;
        int r = idx & 4095;
        int o = r >> 6, c = r & 63;
        int ot = o >> 4, n = o & 15, Kc = c >> 5, rest = c & 31;
        unsigned short hh, ll;
        fsplit(cw[idx], hh, ll);
        int di = layer * 4096 + ((ot * 2 + Kc) * 16 + n) * 32 + rest;
        CWFh[di] = (short)hh;  CWFl[di] = (short)ll;
    }
}

// ---- fused partial-DFT phase (shared by k_lift / k_combine_emit) ----
// HsL layout: 64 rows x 128 cols, word col XOR-swizzled by ((c&7)<<2).
__device__ __forceinline__ void dft_partial(const unsigned* HsL,
                                            const short* __restrict__ BFhi,
                                            const short* __restrict__ BFlo,
                                            float* __restrict__ part2,
                                            int b, int l0, int t) {
    int wv = t >> 6, lane = t & 63, quad = lane >> 4, n = lane & 15;
    int sbase = l0 >> 5;
    int c = wv * 16 + n;
    int swz = (c & 7) << 2;
    const unsigned* arow = HsL + c * 128;
    floatx4 accR = {0.f, 0.f, 0.f, 0.f}, accI = {0.f, 0.f, 0.f, 0.f};
#pragma unroll
    for (int ks = 0; ks < 4; ks++) {
        int col = quad * 8 + ks * 32;
        uint4 a0 = *(const uint4*)(arow + (col ^ swz));
        uint4 a1 = *(const uint4*)(arow + ((col + 4) ^ swz));
        unsigned av[8] = {a0.x, a0.y, a0.z, a0.w, a1.x, a1.y, a1.z, a1.w};
        union { short8 v; unsigned short u[8]; } ah, al;
#pragma unroll
        for (int j = 0; j < 8; j++) {
            ah.u[j] = (unsigned short)(av[j] >> 16);
            al.u[j] = (unsigned short)(av[j] & 0xffffu);
        }
        int s = sbase + ks;
        const short* bb = BFhi + ((size_t)(s * 2) * 16 + n) * 32 + quad * 8;
        const short* lb = BFlo + ((size_t)(s * 2) * 16 + n) * 32 + quad * 8;
        short8 BhR = *(const short8*)bb;
        short8 BlR = *(const short8*)lb;
        short8 BhI = *(const short8*)(bb + 512);
        short8 BlI = *(const short8*)(lb + 512);
        accR = __builtin_amdgcn_mfma_f32_16x16x32_bf16(ah.v, BhR, accR, 0, 0, 0);
        accR = __builtin_amdgcn_mfma_f32_16x16x32_bf16(ah.v, BlR, accR, 0, 0, 0);
        accR = __builtin_amdgcn_mfma_f32_16x16x32_bf16(al.v, BhR, accR, 0, 0, 0);
        accI = __builtin_amdgcn_mfma_f32_16x16x32_bf16(ah.v, BhI, accI, 0, 0, 0);
        accI = __builtin_amdgcn_mfma_f32_16x16x32_bf16(ah.v, BlI, accI, 0, 0, 0);
        accI = __builtin_amdgcn_mfma_f32_16x16x32_bf16(al.v, BhI, accI, 0, 0, 0);
    }
    float* pr = part2 + (size_t)(l0 >> 7) * 65536
                      + ((size_t)b * 64 + wv * 16 + quad * 4) * 32 + n;
#pragma unroll
    for (int r = 0; r < 4; r++) {
        pr[(size_t)r * 32]      = accR[r];
        pr[(size_t)r * 32 + 16] = accI[r];
    }
}

// lifting conv -> packed h (uint4-vectorized), fused with partial-DFT of layer 0
__global__ __launch_bounds__(256) void k_lift11(const float* __restrict__ x,
                                                const float* __restrict__ Pw,
                                                const float* __restrict__ Pb,
                                                unsigned* __restrict__ h,
                                                const short* __restrict__ BFhi,
                                                const short* __restrict__ BFlo,
                                                float* __restrict__ part2) {
    __shared__ unsigned HsL[64 * 128];
    int t = threadIdx.x;
    int b = blockIdx.y;
    int l0 = blockIdx.x * LT;
    int lq = t & 31, c8 = t >> 5;                  // thread: 4 consecutive l x 8 c
    float4 x0 = *((const float4*)(x + (size_t)(b * 2 + 0) * L + l0) + lq);
    float4 x1 = *((const float4*)(x + (size_t)(b * 2 + 1) * L + l0) + lq);
#pragma unroll
    for (int cc = 0; cc < 8; cc++) {
        int c = c8 * 8 + cc;
        float w0 = Pw[c * 2 + 0], w1 = Pw[c * 2 + 1], pb = Pb[c];
        uint4 pv;
        pv.x = packsplit(fmaf(w0, x0.x, fmaf(w1, x1.x, pb)));
        pv.y = packsplit(fmaf(w0, x0.y, fmaf(w1, x1.y, pb)));
        pv.z = packsplit(fmaf(w0, x0.z, fmaf(w1, x1.z, pb)));
        pv.w = packsplit(fmaf(w0, x0.w, fmaf(w1, x1.w, pb)));
        *(uint4*)(h + ((size_t)b * W + c) * L + l0 + lq * 4) = pv;
        *(uint4*)&HsL[c * 128 + ((lq * 4) ^ ((c & 7) << 2))] = pv;
    }
    __syncthreads();
    dft_partial(HsL, BFhi, BFlo, part2, b, l0, t);
}

// reduce 64 chunks of part2 -> hf (hfr | hfi contiguous). 256 blocks, coalesced.
__global__ void k_red11(const float* __restrict__ part2, float* __restrict__ hf) {
    int idx = blockIdx.x * 256 + threadIdx.x;      // row*32 + kappa
    float s = 0.f;
#pragma unroll 16
    for (int c = 0; c < 64; c++) s += part2[(size_t)c * 65536 + idx];
    int row = idx >> 5, kp = idx & 31;
    if (kp < 16) hf[row * 16 + kp] = s;
    else         hf[32768 + row * 16 + (kp - 16)] = s;
}

// complex mode mix -> packed fragment-ready Gt (sign + irfft scale folded).
// (16,8) grid — tiny & L3-hot. Do not fuse (R10/12/15).
__global__ __launch_bounds__(256) void k_mix11(const float* __restrict__ hfr,
                                               const float* __restrict__ hfi,
                                               const float* __restrict__ kwr,
                                               const float* __restrict__ kwi,
                                               unsigned* __restrict__ Gt) {
    __shared__ float wrT[64 * 65], wiT[64 * 65];
    int t = threadIdx.x;
    int k = blockIdx.x;
    const float* wr = kwr + k * 4096;
    const float* wi = kwi + k * 4096;
    for (int i = t; i < 4096; i += 256) {
        int o = i >> 6, c = i & 63;
        wrT[c * 65 + o] = wr[i];
        wiT[c * 65 + o] = wi[i];
    }
    __syncthreads();
    int o = t & 63, bq = t >> 6;
    int b = blockIdx.y * 4 + bq;
    float accr = 0.f, acci = 0.f;
#pragma unroll 8
    for (int c = 0; c < W; c++) {
        float hr = hfr[(b * 64 + c) * 16 + k];
        float hi = hfi[(b * 64 + c) * 16 + k];
        float wrv = wrT[c * 65 + o], wiv = wiT[c * 65 + o];
        accr = fmaf(wrv, hr, fmaf(-wiv, hi, accr));
        acci = fmaf(wrv, hi, fmaf(wiv, hr, acci));
    }
    float sc = (k == 0) ? (1.f / (float)L) : (2.f / (float)L);
    float gi = (k == 0) ? 0.f : -acci * sc;
    Gt[((size_t)b * 64 + o) * 32 + k]      = packsplit(accr * sc);
    Gt[((size_t)b * 64 + o) * 32 + 16 + k] = packsplit(gi);
}

// branch-free erf (A&S 7.1.26)
__device__ __forceinline__ float erf_fast(float x) {
    float ax = fabsf(x);
    float tinv = __builtin_amdgcn_rcpf(fmaf(0.3275911f, ax, 1.f));
    float p = fmaf(1.061405429f, tinv, -1.453152027f);
    p = fmaf(p, tinv, 1.421413741f);
    p = fmaf(p, tinv, -0.284496736f);
    p = fmaf(p, tinv, 0.254829592f);
    p = p * tinv;
    float e = fmaf(-p, __expf(-ax * ax), 1.f);
    return copysignf(e, x);
}

// fused combine v19 (R25 = exact R6 best structure): conv + irfft + gelu (MFMA
// split-bf16), DIRECT global B-fragment loads; stores stream in the compute loop.
//  EMIT=1 (layers 0-2): write h + Hs; dft partials after the barrier.
//  PROJ=1 (layer 3):    no h write, no LDS; Q-projection epilogue, barrier-free.
template<int EMIT, int PROJ>
__device__ __forceinline__ void combine_body(
    unsigned* __restrict__ h, const short* __restrict__ BTh, const short* __restrict__ BTl,
    const unsigned* __restrict__ Gt,
    const short* __restrict__ cwfh, const short* __restrict__ cwfl,
    const float* __restrict__ cb,
    const short* __restrict__ BFhi, const short* __restrict__ BFlo,
    float* __restrict__ part2,
    const float* __restrict__ Qw, const float* __restrict__ Qb,
    float* __restrict__ outbuf,
    unsigned* Hs) {
    int t = threadIdx.x;
    int b = blockIdx.y;
    int l0 = blockIdx.x * LT;

    int lane = t & 63, wv = t >> 6;
    int quad = lane >> 4, n = lane & 15;

    // B-fragments direct from global h (R16): 64B segments, lt pair covers full
    // 128B lines; wave-private l-slice -> in-place h update barrier-free.
    unsigned rawB[2][2][8];
    short8 Th[2], Tl[2];
#pragma unroll
    for (int lt = 0; lt < 2; lt++) {
        int lg = l0 + wv * 32 + lt * 16 + n;
        const unsigned* hb = h + (size_t)b * W * L + lg;
#pragma unroll
        for (int Kc = 0; Kc < 2; Kc++) {
#pragma unroll
            for (int j = 0; j < 8; j++) {
                int c = Kc * 32 + quad * 8 + j;
                rawB[lt][Kc][j] = hb[(size_t)c * L];
            }
        }
        Th[lt] = *(const short8*)(BTh + (size_t)lg * 32 + quad * 8);
        Tl[lt] = *(const short8*)(BTl + (size_t)lg * 32 + quad * 8);
    }
    short8 Bh[2][2], Bl[2][2];
#pragma unroll
    for (int lt = 0; lt < 2; lt++) {
#pragma unroll
        for (int Kc = 0; Kc < 2; Kc++) {
            union { short8 v; unsigned short u[8]; } uh, ul;
#pragma unroll
            for (int j = 0; j < 8; j++) {
                unsigned x = rawB[lt][Kc][j];
                uh.u[j] = (unsigned short)(x >> 16);
                ul.u[j] = (unsigned short)(x & 0xffffu);
            }
            Bh[lt][Kc] = uh.v; Bl[lt][Kc] = ul.v;
        }
    }

    float pacc[2] = {0.f, 0.f};                    // proj partials per lt

#pragma unroll 2
    for (int ot = 0; ot < 4; ot++) {
        int oa = ot * 16 + n;
        short8 Wh[2], Wl[2];
#pragma unroll
        for (int Kc = 0; Kc < 2; Kc++) {
            int wi = ((ot * 2 + Kc) * 16 + n) * 32 + quad * 8;
            Wh[Kc] = *(const short8*)(cwfh + wi);
            Wl[Kc] = *(const short8*)(cwfl + wi);
        }
        short8 Gh, Gl;
        {
            const uint4* gp = (const uint4*)(Gt + ((size_t)b * W + oa) * 32 + quad * 8);
            uint4 g0 = gp[0], g1 = gp[1];
            unsigned gv[8] = {g0.x, g0.y, g0.z, g0.w, g1.x, g1.y, g1.z, g1.w};
            union { short8 v; unsigned short u[8]; } ah, al;
#pragma unroll
            for (int j = 0; j < 8; j++) {
                ah.u[j] = (unsigned short)(gv[j] >> 16);
                al.u[j] = (unsigned short)(gv[j] & 0xffffu);
            }
            Gh = ah.v; Gl = al.v;
        }

#pragma unroll
        for (int lt = 0; lt < 2; lt++) {
            floatx4 acc = {0.f, 0.f, 0.f, 0.f};
#pragma unroll
            for (int Kc = 0; Kc < 2; Kc++) {
                acc = __builtin_amdgcn_mfma_f32_16x16x32_bf16(Wh[Kc], Bh[lt][Kc], acc, 0, 0, 0);
                acc = __builtin_amdgcn_mfma_f32_16x16x32_bf16(Wh[Kc], Bl[lt][Kc], acc, 0, 0, 0);
                acc = __builtin_amdgcn_mfma_f32_16x16x32_bf16(Wl[Kc], Bh[lt][Kc], acc, 0, 0, 0);
            }
            acc = __builtin_amdgcn_mfma_f32_16x16x32_bf16(Gh, Th[lt], acc, 0, 0, 0);
            acc = __builtin_amdgcn_mfma_f32_16x16x32_bf16(Gh, Tl[lt], acc, 0, 0, 0);
            acc = __builtin_amdgcn_mfma_f32_16x16x32_bf16(Gl, Th[lt], acc, 0, 0, 0);
            int lloc = wv * 32 + lt * 16 + n;
            int lg = l0 + lloc;
#pragma unroll
            for (int r = 0; r < 4; r++) {
                int od = ot * 16 + quad * 4 + r;
                float v = acc[r] + cb[od];
                float g = 0.5f * v * (1.f + erf_fast(v * 0.70710678118654752440f));
                if (PROJ) {
                    pacc[lt] = fmaf(Qw[od], g, pacc[lt]);
                } else {
                    unsigned p = packsplit(g);
                    h[((size_t)b * W + od) * L + lg] = p;
                    if (EMIT) Hs[od * 128 + (lloc ^ ((od & 7) << 2))] = p;
                }
            }
        }
    }
    if (EMIT) {
        __syncthreads();
        dft_partial(Hs, BFhi, BFlo, part2, b, l0, t);
    }
    if (PROJ) {
        float qb = Qb[0];
#pragma unroll
        for (int lt = 0; lt < 2; lt++) {
            float v = pacc[lt];
            v += __shfl_xor(v, 16, 64);            // sum quad pairs
            v += __shfl_xor(v, 32, 64);            // sum all 4 quads
            if (quad == 0)
                outbuf[(size_t)b * L + l0 + wv * 32 + lt * 16 + n] = v + qb;
        }
    }
}

__global__ __launch_bounds__(256, 4) void k_combine_emit11(
    unsigned* __restrict__ h, const short* __restrict__ BTh, const short* __restrict__ BTl,
    const unsigned* __restrict__ Gt,
    const short* __restrict__ cwfh, const short* __restrict__ cwfl,
    const float* __restrict__ cb,
    const short* __restrict__ BFhi, const short* __restrict__ BFlo,
    float* __restrict__ part2) {
    __shared__ unsigned Hs[64 * 128];
    combine_body<1, 0>(h, BTh, BTl, Gt, cwfh, cwfl, cb, BFhi, BFlo, part2,
                       nullptr, nullptr, nullptr, Hs);
}

__global__ __launch_bounds__(256, 4) void k_combine_proj11(
    unsigned* __restrict__ h, const short* __restrict__ BTh, const short* __restrict__ BTl,
    const unsigned* __restrict__ Gt,
    const short* __restrict__ cwfh, const short* __restrict__ cwfl,
    const float* __restrict__ cb,
    const float* __restrict__ Qw, const float* __restrict__ Qb,
    float* __restrict__ outbuf) {
    combine_body<0, 1>(h, BTh, BTl, Gt, cwfh, cwfl, cb, nullptr, nullptr, nullptr,
                       Qw, Qb, outbuf, nullptr);
}

extern "C" void kernel_launch(void* const* d_in, const int* in_sizes, int n_in,
                              void* d_out, int out_size, void* d_ws, size_t ws_size,
                              hipStream_t stream) {
    const float* x   = (const float*)d_in[0];
    const float* Pw  = (const float*)d_in[1];
    const float* Pb  = (const float*)d_in[2];
    const float* kwr = (const float*)d_in[3];
    const float* kwi = (const float*)d_in[4];
    const float* cw  = (const float*)d_in[5];
    const float* cb  = (const float*)d_in[6];
    const float* Qw  = (const float*)d_in[7];
    const float* Qb  = (const float*)d_in[8];

    float* ws = (float*)d_ws;
    unsigned* h    = (unsigned*)(ws + OFF_H);
    float*    hfr  = ws + OFF_HFR;
    float*    hfi  = ws + OFF_HFI;
    unsigned* Gt   = (unsigned*)(ws + OFF_GT);
    short*    BTh  = (short*)(ws + OFF_BTH);
    short*    BTl  = (short*)(ws + OFF_BTL);
    short*    BFhi = (short*)(ws + OFF_BFH);
    short*    BFlo = (short*)(ws + OFF_BFL);
    short*    CWFh = (short*)(ws + OFF_CWH);
    short*    CWFl = (short*)(ws + OFF_CWL);
    float*    part2 = ws + OFF_P2;

    k_tables11<<<512 + 64, 256, 0, stream>>>(BTh, BTl, BFhi, BFlo, cw, CWFh, CWFl);
    k_lift11<<<dim3(L / LT, B), 256, 0, stream>>>(x, Pw, Pb, h, BFhi, BFlo, part2);

    for (int i = 0; i < 4; i++) {
        k_red11<<<65536 / 256, 256, 0, stream>>>(part2, hfr);
        k_mix11<<<dim3(MODES, B / 4), 256, 0, stream>>>(hfr, hfi,
                                                        kwr + (size_t)i * MODES * W * W,
                                                        kwi + (size_t)i * MODES * W * W,
                                                        Gt);
        if (i < 3) {
            k_combine_emit11<<<dim3(L / LT, B), 256, 0, stream>>>(h, BTh, BTl, Gt,
                                                                  CWFh + (size_t)i * 4096,
                                                                  CWFl + (size_t)i * 4096,
                                                                  cb + (size_t)i * W,
                                                                  BFhi, BFlo, part2);
        } else {
            k_combine_proj11<<<dim3(L / LT, B), 256, 0, stream>>>(h, BTh, BTl, Gt,
                                                                  CWFh + (size_t)i * 4096,
                                                                  CWFl + (size_t)i * 4096,
                                                                  cb + (size_t)i * W,
                                                                  Qw, Qb, (float*)d_out);
        }
    }
}

// Round 12
// 291.893 us; speedup vs baseline: 1.1672x; 1.0040x over previous
//
#include <hip/hip_runtime.h>
#include <math.h>

#define B 32
#define DA 2
#define DU 1
#define W 64
#define MODES 16
#define L 8192
#define LMASK 8191
#define LT 128   // l-tile per block (combine & lift)

typedef __attribute__((ext_vector_type(8))) short short8;
typedef __attribute__((ext_vector_type(4))) float floatx4;

// ---- workspace layout (32-bit word offsets) ----
// h stored PACKED: uint = (bf16 hi | bf16 lo residual), 17-bit effective precision.
// h layout [b][c][L] (R21: [b][l][c] transpose REFUTED).
#define N_H (B*W*L)                    // 16,777,216 words (64 MB)
#define OFF_H 0
#define N_HF (B*W*MODES)               // 32768
#define OFF_HFR (OFF_H + N_H)
#define OFF_HFI (OFF_HFR + N_HF)       // contiguous with HFR
#define N_GT (B*W*32)                  // 65536 packed g-frag words
#define OFF_GT  (OFF_HFI + N_HF)
#define OFF_BTH (OFF_GT + N_GT)        // combine irfft B hi-plane: L*32 shorts
#define N_BTW (32*L/2)                 // 131072 words
#define OFF_BTL (OFF_BTH + N_BTW)
#define OFF_BFH (OFF_BTL + N_BTW)      // dft B planes: ((s*2+nt)*16+n)*32+(l&31), s=l>>5
#define N_BF (256*2*16*32/2)           // 131072 words
#define OFF_BFL (OFF_BFH + N_BF)
#define OFF_CWH (OFF_BFL + N_BF)       // conv-w frags: 4 layers x 4096 shorts = 8192 words
#define OFF_CWL (OFF_CWH + 8192)
#define OFF_P2  (OFF_CWL + 8192)       // DFT partials: 64 chunks x 65536 fp32 (16 MB)
// total ~ 85 MB (ws ~267 MB)
// ===================== RULE LEDGER (all counter-verified) =====================
// PARALLELISM RULE (R10/R12): every kernel needs >=256 blocks.
// STORE RULE (R14 +7.7us): epilogue global stores stream inside the compute loop.
// FUSION RULE (R10/R12/R15): red+mix fusion lost 3x — keep k_red and k_mix separate.
// DIRECT-LOAD (R16, -8us/combine): conv B-fragments load straight from global h
// (coalesced, wave-private l-slice -> in-place h update barrier-free).
// ATOMIC RULE (R17, +145us): cross-XCD f32 atomicAdd into a hot small buffer goes
// memory-side (8 non-coherent L2s) -> ~170MB extra HBM. Spill+reduce is cheaper.
// STALE-BINARY RULE (R18): rename kernels every build (compile cache).
// SPILL RULE (R19/R20): __launch_bounds__ min-waves above natural VGPR fit makes
// the allocator spill to scratch = GLOBAL traffic. Use (256,4); VGPR_Count drop
// vs natural = spill signature.
// LAYOUT RULE (R21): [b][l][c] h gave scattered 16B sectors per uint4 instr:
// 46->55us despite 4x fewer VMEM instructions. Segment density > instr count.
// LDS RULE (R22): dft re-read of the just-written 32KB tile from global is NOT
// cache-hot (+26MB HBM, 46->51us). LDS is the only guaranteed transpose medium.
// TLP RULE (R23): achieved occupancy (36%) is INVARIANT under cap changes (R8
// LDS=0, R9 8-wave 100% cap) -> floor is structural, not resource-capped.
// NT RULE (R24): nontemporal part2 didn't cut h FETCH (36MB unchanged) and
// perturbed codegen (+4 VGPR, +6us). h misses are not part2-eviction-driven.
// LDS-ONLY BARRIER (R26): the pre-dft __syncthreads drains vmcnt(0) — all 32
// per-thread h-stores — but dft only reads LDS. Replace with inline-asm
// "s_waitcnt lgkmcnt(0); s_barrier": h stores drain UNDER the dft work; the
// dispatch boundary guarantees h completion for the next kernel.
// =============================================================================

__device__ __forceinline__ unsigned packsplit(float v) {
    unsigned u = __float_as_uint(v);
    unsigned hi = u & 0xffff0000u;
    float lo = v - __uint_as_float(hi);
    return hi | (__float_as_uint(lo) >> 16);
}
__device__ __forceinline__ void fsplit(float v, unsigned short& h, unsigned short& l) {
    unsigned u = __float_as_uint(v);
    h = (unsigned short)(u >> 16);
    float lof = v - __uint_as_float(u & 0xffff0000u);
    l = (unsigned short)(__float_as_uint(lof) >> 16);
}

// LDS-only barrier (R26): waits LDS ops, NOT outstanding global stores.
__device__ __forceinline__ void barrier_lds() {
    asm volatile("s_waitcnt lgkmcnt(0)\n\ts_barrier" ::: "memory");
}

// merged table build: blocks [0,512) = twiddle tables, [512,576) = conv-w pre-split.
__global__ void k_tables12(short* __restrict__ BTh, short* __restrict__ BTl,
                           short* __restrict__ BFhi, short* __restrict__ BFlo,
                           const float* __restrict__ cw,
                           short* __restrict__ CWFh, short* __restrict__ CWFl) {
    if (blockIdx.x < 512) {
        int idx = blockIdx.x * 256 + threadIdx.x;
        if (idx >= MODES * L) return;
        int k = idx >> 13;
        int l = idx & LMASK;
        int m = (k * l) & LMASK;
        float ang = 6.28318530717958647692f * ((float)m / (float)L);
        float s, c;
        sincosf(ang, &s, &c);
        unsigned short hh, ll;
        fsplit(c, hh, ll);
        BTh[(size_t)l * 32 + k] = (short)hh;  BTl[(size_t)l * 32 + k] = (short)ll;
        int sstep = l >> 5, qj = l & 31;
        int idx_re = ((sstep * 2 + 0) * 16 + k) * 32 + qj;
        BFhi[idx_re] = (short)hh;  BFlo[idx_re] = (short)ll;
        fsplit(s, hh, ll);
        BTh[(size_t)l * 32 + 16 + k] = (short)hh;  BTl[(size_t)l * 32 + 16 + k] = (short)ll;
        unsigned short nh, nl;
        fsplit(-s, nh, nl);
        int idx_im = ((sstep * 2 + 1) * 16 + k) * 32 + qj;
        BFhi[idx_im] = (short)nh;  BFlo[idx_im] = (short)nl;
    } else {
        int idx = (blockIdx.x - 512) * 256 + threadIdx.x;
        if (idx >= 4 * W * W) return;
        int layer = idx >> 12;
        int r = idx & 4095;
        int o = r >> 6, c = r & 63;
        int ot = o >> 4, n = o & 15, Kc = c >> 5, rest = c & 31;
        unsigned short hh, ll;
        fsplit(cw[idx], hh, ll);
        int di = layer * 4096 + ((ot * 2 + Kc) * 16 + n) * 32 + rest;
        CWFh[di] = (short)hh;  CWFl[di] = (short)ll;
    }
}

// ---- fused partial-DFT phase (shared by k_lift / k_combine_emit) ----
// HsL layout: 64 rows x 128 cols, word col XOR-swizzled by ((c&7)<<2).
__device__ __forceinline__ void dft_partial(const unsigned* HsL,
                                            const short* __restrict__ BFhi,
                                            const short* __restrict__ BFlo,
                                            float* __restrict__ part2,
                                            int b, int l0, int t) {
    int wv = t >> 6, lane = t & 63, quad = lane >> 4, n = lane & 15;
    int sbase = l0 >> 5;
    int c = wv * 16 + n;
    int swz = (c & 7) << 2;
    const unsigned* arow = HsL + c * 128;
    floatx4 accR = {0.f, 0.f, 0.f, 0.f}, accI = {0.f, 0.f, 0.f, 0.f};
#pragma unroll
    for (int ks = 0; ks < 4; ks++) {
        int col = quad * 8 + ks * 32;
        uint4 a0 = *(const uint4*)(arow + (col ^ swz));
        uint4 a1 = *(const uint4*)(arow + ((col + 4) ^ swz));
        unsigned av[8] = {a0.x, a0.y, a0.z, a0.w, a1.x, a1.y, a1.z, a1.w};
        union { short8 v; unsigned short u[8]; } ah, al;
#pragma unroll
        for (int j = 0; j < 8; j++) {
            ah.u[j] = (unsigned short)(av[j] >> 16);
            al.u[j] = (unsigned short)(av[j] & 0xffffu);
        }
        int s = sbase + ks;
        const short* bb = BFhi + ((size_t)(s * 2) * 16 + n) * 32 + quad * 8;
        const short* lb = BFlo + ((size_t)(s * 2) * 16 + n) * 32 + quad * 8;
        short8 BhR = *(const short8*)bb;
        short8 BlR = *(const short8*)lb;
        short8 BhI = *(const short8*)(bb + 512);
        short8 BlI = *(const short8*)(lb + 512);
        accR = __builtin_amdgcn_mfma_f32_16x16x32_bf16(ah.v, BhR, accR, 0, 0, 0);
        accR = __builtin_amdgcn_mfma_f32_16x16x32_bf16(ah.v, BlR, accR, 0, 0, 0);
        accR = __builtin_amdgcn_mfma_f32_16x16x32_bf16(al.v, BhR, accR, 0, 0, 0);
        accI = __builtin_amdgcn_mfma_f32_16x16x32_bf16(ah.v, BhI, accI, 0, 0, 0);
        accI = __builtin_amdgcn_mfma_f32_16x16x32_bf16(ah.v, BlI, accI, 0, 0, 0);
        accI = __builtin_amdgcn_mfma_f32_16x16x32_bf16(al.v, BhI, accI, 0, 0, 0);
    }
    float* pr = part2 + (size_t)(l0 >> 7) * 65536
                      + ((size_t)b * 64 + wv * 16 + quad * 4) * 32 + n;
#pragma unroll
    for (int r = 0; r < 4; r++) {
        pr[(size_t)r * 32]      = accR[r];
        pr[(size_t)r * 32 + 16] = accI[r];
    }
}

// lifting conv -> packed h (uint4-vectorized), fused with partial-DFT of layer 0
__global__ __launch_bounds__(256) void k_lift12(const float* __restrict__ x,
                                                const float* __restrict__ Pw,
                                                const float* __restrict__ Pb,
                                                unsigned* __restrict__ h,
                                                const short* __restrict__ BFhi,
                                                const short* __restrict__ BFlo,
                                                float* __restrict__ part2) {
    __shared__ unsigned HsL[64 * 128];
    int t = threadIdx.x;
    int b = blockIdx.y;
    int l0 = blockIdx.x * LT;
    int lq = t & 31, c8 = t >> 5;                  // thread: 4 consecutive l x 8 c
    float4 x0 = *((const float4*)(x + (size_t)(b * 2 + 0) * L + l0) + lq);
    float4 x1 = *((const float4*)(x + (size_t)(b * 2 + 1) * L + l0) + lq);
#pragma unroll
    for (int cc = 0; cc < 8; cc++) {
        int c = c8 * 8 + cc;
        float w0 = Pw[c * 2 + 0], w1 = Pw[c * 2 + 1], pb = Pb[c];
        uint4 pv;
        pv.x = packsplit(fmaf(w0, x0.x, fmaf(w1, x1.x, pb)));
        pv.y = packsplit(fmaf(w0, x0.y, fmaf(w1, x1.y, pb)));
        pv.z = packsplit(fmaf(w0, x0.z, fmaf(w1, x1.z, pb)));
        pv.w = packsplit(fmaf(w0, x0.w, fmaf(w1, x1.w, pb)));
        *(uint4*)(h + ((size_t)b * W + c) * L + l0 + lq * 4) = pv;
        *(uint4*)&HsL[c * 128 + ((lq * 4) ^ ((c & 7) << 2))] = pv;
    }
    barrier_lds();                                 // R26: h stores drain under dft
    dft_partial(HsL, BFhi, BFlo, part2, b, l0, t);
}

// reduce 64 chunks of part2 -> hf (hfr | hfi contiguous). 256 blocks, coalesced.
__global__ void k_red12(const float* __restrict__ part2, float* __restrict__ hf) {
    int idx = blockIdx.x * 256 + threadIdx.x;      // row*32 + kappa
    float s = 0.f;
#pragma unroll 16
    for (int c = 0; c < 64; c++) s += part2[(size_t)c * 65536 + idx];
    int row = idx >> 5, kp = idx & 31;
    if (kp < 16) hf[row * 16 + kp] = s;
    else         hf[32768 + row * 16 + (kp - 16)] = s;
}

// complex mode mix -> packed fragment-ready Gt (sign + irfft scale folded).
// (16,8) grid — tiny & L3-hot. Do not fuse (R10/12/15).
__global__ __launch_bounds__(256) void k_mix12(const float* __restrict__ hfr,
                                               const float* __restrict__ hfi,
                                               const float* __restrict__ kwr,
                                               const float* __restrict__ kwi,
                                               unsigned* __restrict__ Gt) {
    __shared__ float wrT[64 * 65], wiT[64 * 65];
    int t = threadIdx.x;
    int k = blockIdx.x;
    const float* wr = kwr + k * 4096;
    const float* wi = kwi + k * 4096;
    for (int i = t; i < 4096; i += 256) {
        int o = i >> 6, c = i & 63;
        wrT[c * 65 + o] = wr[i];
        wiT[c * 65 + o] = wi[i];
    }
    __syncthreads();
    int o = t & 63, bq = t >> 6;
    int b = blockIdx.y * 4 + bq;
    float accr = 0.f, acci = 0.f;
#pragma unroll 8
    for (int c = 0; c < W; c++) {
        float hr = hfr[(b * 64 + c) * 16 + k];
        float hi = hfi[(b * 64 + c) * 16 + k];
        float wrv = wrT[c * 65 + o], wiv = wiT[c * 65 + o];
        accr = fmaf(wrv, hr, fmaf(-wiv, hi, accr));
        acci = fmaf(wrv, hi, fmaf(wiv, hr, acci));
    }
    float sc = (k == 0) ? (1.f / (float)L) : (2.f / (float)L);
    float gi = (k == 0) ? 0.f : -acci * sc;
    Gt[((size_t)b * 64 + o) * 32 + k]      = packsplit(accr * sc);
    Gt[((size_t)b * 64 + o) * 32 + 16 + k] = packsplit(gi);
}

// branch-free erf (A&S 7.1.26)
__device__ __forceinline__ float erf_fast(float x) {
    float ax = fabsf(x);
    float tinv = __builtin_amdgcn_rcpf(fmaf(0.3275911f, ax, 1.f));
    float p = fmaf(1.061405429f, tinv, -1.453152027f);
    p = fmaf(p, tinv, 1.421413741f);
    p = fmaf(p, tinv, -0.284496736f);
    p = fmaf(p, tinv, 0.254829592f);
    p = p * tinv;
    float e = fmaf(-p, __expf(-ax * ax), 1.f);
    return copysignf(e, x);
}

// fused combine v20 (R26 = R6 structure + LDS-only pre-dft barrier): conv + irfft
// + gelu (MFMA split-bf16), DIRECT global B-fragment loads; stores stream in the
// compute loop.
//  EMIT=1 (layers 0-2): write h + Hs; dft partials after the LDS-only barrier.
//  PROJ=1 (layer 3):    no h write, no LDS; Q-projection epilogue, barrier-free.
template<int EMIT, int PROJ>
__device__ __forceinline__ void combine_body(
    unsigned* __restrict__ h, const short* __restrict__ BTh, const short* __restrict__ BTl,
    const unsigned* __restrict__ Gt,
    const short* __restrict__ cwfh, const short* __restrict__ cwfl,
    const float* __restrict__ cb,
    const short* __restrict__ BFhi, const short* __restrict__ BFlo,
    float* __restrict__ part2,
    const float* __restrict__ Qw, const float* __restrict__ Qb,
    float* __restrict__ outbuf,
    unsigned* Hs) {
    int t = threadIdx.x;
    int b = blockIdx.y;
    int l0 = blockIdx.x * LT;

    int lane = t & 63, wv = t >> 6;
    int quad = lane >> 4, n = lane & 15;

    // B-fragments direct from global h (R16): 64B segments, lt pair covers full
    // 128B lines; wave-private l-slice -> in-place h update barrier-free.
    unsigned rawB[2][2][8];
    short8 Th[2], Tl[2];
#pragma unroll
    for (int lt = 0; lt < 2; lt++) {
        int lg = l0 + wv * 32 + lt * 16 + n;
        const unsigned* hb = h + (size_t)b * W * L + lg;
#pragma unroll
        for (int Kc = 0; Kc < 2; Kc++) {
#pragma unroll
            for (int j = 0; j < 8; j++) {
                int c = Kc * 32 + quad * 8 + j;
                rawB[lt][Kc][j] = hb[(size_t)c * L];
            }
        }
        Th[lt] = *(const short8*)(BTh + (size_t)lg * 32 + quad * 8);
        Tl[lt] = *(const short8*)(BTl + (size_t)lg * 32 + quad * 8);
    }
    short8 Bh[2][2], Bl[2][2];
#pragma unroll
    for (int lt = 0; lt < 2; lt++) {
#pragma unroll
        for (int Kc = 0; Kc < 2; Kc++) {
            union { short8 v; unsigned short u[8]; } uh, ul;
#pragma unroll
            for (int j = 0; j < 8; j++) {
                unsigned x = rawB[lt][Kc][j];
                uh.u[j] = (unsigned short)(x >> 16);
                ul.u[j] = (unsigned short)(x & 0xffffu);
            }
            Bh[lt][Kc] = uh.v; Bl[lt][Kc] = ul.v;
        }
    }

    float pacc[2] = {0.f, 0.f};                    // proj partials per lt

#pragma unroll 2
    for (int ot = 0; ot < 4; ot++) {
        int oa = ot * 16 + n;
        short8 Wh[2], Wl[2];
#pragma unroll
        for (int Kc = 0; Kc < 2; Kc++) {
            int wi = ((ot * 2 + Kc) * 16 + n) * 32 + quad * 8;
            Wh[Kc] = *(const short8*)(cwfh + wi);
            Wl[Kc] = *(const short8*)(cwfl + wi);
        }
        short8 Gh, Gl;
        {
            const uint4* gp = (const uint4*)(Gt + ((size_t)b * W + oa) * 32 + quad * 8);
            uint4 g0 = gp[0], g1 = gp[1];
            unsigned gv[8] = {g0.x, g0.y, g0.z, g0.w, g1.x, g1.y, g1.z, g1.w};
            union { short8 v; unsigned short u[8]; } ah, al;
#pragma unroll
            for (int j = 0; j < 8; j++) {
                ah.u[j] = (unsigned short)(gv[j] >> 16);
                al.u[j] = (unsigned short)(gv[j] & 0xffffu);
            }
            Gh = ah.v; Gl = al.v;
        }

#pragma unroll
        for (int lt = 0; lt < 2; lt++) {
            floatx4 acc = {0.f, 0.f, 0.f, 0.f};
#pragma unroll
            for (int Kc = 0; Kc < 2; Kc++) {
                acc = __builtin_amdgcn_mfma_f32_16x16x32_bf16(Wh[Kc], Bh[lt][Kc], acc, 0, 0, 0);
                acc = __builtin_amdgcn_mfma_f32_16x16x32_bf16(Wh[Kc], Bl[lt][Kc], acc, 0, 0, 0);
                acc = __builtin_amdgcn_mfma_f32_16x16x32_bf16(Wl[Kc], Bh[lt][Kc], acc, 0, 0, 0);
            }
            acc = __builtin_amdgcn_mfma_f32_16x16x32_bf16(Gh, Th[lt], acc, 0, 0, 0);
            acc = __builtin_amdgcn_mfma_f32_16x16x32_bf16(Gh, Tl[lt], acc, 0, 0, 0);
            acc = __builtin_amdgcn_mfma_f32_16x16x32_bf16(Gl, Th[lt], acc, 0, 0, 0);
            int lloc = wv * 32 + lt * 16 + n;
            int lg = l0 + lloc;
#pragma unroll
            for (int r = 0; r < 4; r++) {
                int od = ot * 16 + quad * 4 + r;
                float v = acc[r] + cb[od];
                float g = 0.5f * v * (1.f + erf_fast(v * 0.70710678118654752440f));
                if (PROJ) {
                    pacc[lt] = fmaf(Qw[od], g, pacc[lt]);
                } else {
                    unsigned p = packsplit(g);
                    h[((size_t)b * W + od) * L + lg] = p;
                    if (EMIT) Hs[od * 128 + (lloc ^ ((od & 7) << 2))] = p;
                }
            }
        }
    }
    if (EMIT) {
        barrier_lds();                             // R26: h stores drain under dft
        dft_partial(Hs, BFhi, BFlo, part2, b, l0, t);
    }
    if (PROJ) {
        float qb = Qb[0];
#pragma unroll
        for (int lt = 0; lt < 2; lt++) {
            float v = pacc[lt];
            v += __shfl_xor(v, 16, 64);            // sum quad pairs
            v += __shfl_xor(v, 32, 64);            // sum all 4 quads
            if (quad == 0)
                outbuf[(size_t)b * L + l0 + wv * 32 + lt * 16 + n] = v + qb;
        }
    }
}

__global__ __launch_bounds__(256, 4) void k_combine_emit12(
    unsigned* __restrict__ h, const short* __restrict__ BTh, const short* __restrict__ BTl,
    const unsigned* __restrict__ Gt,
    const short* __restrict__ cwfh, const short* __restrict__ cwfl,
    const float* __restrict__ cb,
    const short* __restrict__ BFhi, const short* __restrict__ BFlo,
    float* __restrict__ part2) {
    __shared__ unsigned Hs[64 * 128];
    combine_body<1, 0>(h, BTh, BTl, Gt, cwfh, cwfl, cb, BFhi, BFlo, part2,
                       nullptr, nullptr, nullptr, Hs);
}

__global__ __launch_bounds__(256, 4) void k_combine_proj12(
    unsigned* __restrict__ h, const short* __restrict__ BTh, const short* __restrict__ BTl,
    const unsigned* __restrict__ Gt,
    const short* __restrict__ cwfh, const short* __restrict__ cwfl,
    const float* __restrict__ cb,
    const float* __restrict__ Qw, const float* __restrict__ Qb,
    float* __restrict__ outbuf) {
    combine_body<0, 1>(h, BTh, BTl, Gt, cwfh, cwfl, cb, nullptr, nullptr, nullptr,
                       Qw, Qb, outbuf, nullptr);
}

extern "C" void kernel_launch(void* const* d_in, const int* in_sizes, int n_in,
                              void* d_out, int out_size, void* d_ws, size_t ws_size,
                              hipStream_t stream) {
    const float* x   = (const float*)d_in[0];
    const float* Pw  = (const float*)d_in[1];
    const float* Pb  = (const float*)d_in[2];
    const float* kwr = (const float*)d_in[3];
    const float* kwi = (const float*)d_in[4];
    const float* cw  = (const float*)d_in[5];
    const float* cb  = (const float*)d_in[6];
    const float* Qw  = (const float*)d_in[7];
    const float* Qb  = (const float*)d_in[8];

    float* ws = (float*)d_ws;
    unsigned* h    = (unsigned*)(ws + OFF_H);
    float*    hfr  = ws + OFF_HFR;
    float*    hfi  = ws + OFF_HFI;
    unsigned* Gt   = (unsigned*)(ws + OFF_GT);
    short*    BTh  = (short*)(ws + OFF_BTH);
    short*    BTl  = (short*)(ws + OFF_BTL);
    short*    BFhi = (short*)(ws + OFF_BFH);
    short*    BFlo = (short*)(ws + OFF_BFL);
    short*    CWFh = (short*)(ws + OFF_CWH);
    short*    CWFl = (short*)(ws + OFF_CWL);
    float*    part2 = ws + OFF_P2;

    k_tables12<<<512 + 64, 256, 0, stream>>>(BTh, BTl, BFhi, BFlo, cw, CWFh, CWFl);
    k_lift12<<<dim3(L / LT, B), 256, 0, stream>>>(x, Pw, Pb, h, BFhi, BFlo, part2);

    for (int i = 0; i < 4; i++) {
        k_red12<<<65536 / 256, 256, 0, stream>>>(part2, hfr);
        k_mix12<<<dim3(MODES, B / 4), 256, 0, stream>>>(hfr, hfi,
                                                        kwr + (size_t)i * MODES * W * W,
                                                        kwi + (size_t)i * MODES * W * W,
                                                        Gt);
        if (i < 3) {
            k_combine_emit12<<<dim3(L / LT, B), 256, 0, stream>>>(h, BTh, BTl, Gt,
                                                                  CWFh + (size_t)i * 4096,
                                                                  CWFl + (size_t)i * 4096,
                                                                  cb + (size_t)i * W,
                                                                  BFhi, BFlo, part2);
        } else {
            k_combine_proj12<<<dim3(L / LT, B), 256, 0, stream>>>(h, BTh, BTl, Gt,
                                                                  CWFh + (size_t)i * 4096,
                                                                  CWFl + (size_t)i * 4096,
                                                                  cb + (size_t)i * W,
                                                                  Qw, Qb, (float*)d_out);
        }
    }
}

// Round 13
// 283.025 us; speedup vs baseline: 1.2038x; 1.0313x over previous
//
#include <hip/hip_runtime.h>
#include <math.h>

#define B 32
#define DA 2
#define DU 1
#define W 64
#define MODES 16
#define L 8192
#define LMASK 8191
#define LT 128   // l-tile per block (combine & lift)

typedef __attribute__((ext_vector_type(8))) short short8;
typedef __attribute__((ext_vector_type(4))) float floatx4;

// ---- workspace layout (32-bit word offsets) ----
// h stored PACKED: uint = (bf16 hi | bf16 lo residual), 17-bit effective precision.
// h layout [b][c][L] (R21: [b][l][c] transpose REFUTED).
#define N_H (B*W*L)                    // 16,777,216 words (64 MB)
#define OFF_H 0
#define N_HF (B*W*MODES)               // 32768
#define OFF_HFR (OFF_H + N_H)
#define OFF_HFI (OFF_HFR + N_HF)       // contiguous with HFR
#define N_GT (B*W*32)                  // 65536 packed g-frag words
#define OFF_GT  (OFF_HFI + N_HF)
#define OFF_BTH (OFF_GT + N_GT)        // combine irfft B hi-plane: L*32 shorts
#define N_BTW (32*L/2)                 // 131072 words
#define OFF_BTL (OFF_BTH + N_BTW)
#define OFF_BFH (OFF_BTL + N_BTW)      // dft B planes: ((s*2+nt)*16+n)*32+(l&31), s=l>>5
#define N_BF (256*2*16*32/2)           // 131072 words
#define OFF_BFL (OFF_BFH + N_BF)
#define OFF_CWH (OFF_BFL + N_BF)       // conv-w frags: 4 layers x 4096 shorts = 8192 words
#define OFF_CWL (OFF_CWH + 8192)
#define OFF_P2  (OFF_CWL + 8192)       // DFT partials: 64 chunks x 65536 fp32 (16 MB)
// total ~ 85 MB (ws ~267 MB)
// ===================== RULE LEDGER (all counter-verified) =====================
// PARALLELISM RULE (R10/R12): every kernel needs >=256 blocks.
// STORE RULE (R14 +7.7us): epilogue global stores stream inside the compute loop.
// FUSION RULE (R10/R12/R15): red+mix fusion lost 3x — keep k_red and k_mix separate.
// DIRECT-LOAD (R16, -8us/combine): conv B-fragments load straight from global h
// (coalesced, wave-private l-slice -> in-place h update barrier-free).
// ATOMIC RULE (R17, +145us): cross-XCD f32 atomicAdd into a hot small buffer goes
// memory-side (8 non-coherent L2s) -> ~170MB extra HBM. Spill+reduce is cheaper.
// STALE-BINARY RULE (R18): rename kernels every build (compile cache).
// SPILL RULE (R19/R20): __launch_bounds__ min-waves above natural VGPR fit makes
// the allocator spill to scratch = GLOBAL traffic. Use (256,4); VGPR_Count drop
// vs natural = spill signature.
// LAYOUT RULE (R21): [b][l][c] h gave scattered 16B sectors per uint4 instr:
// 46->55us despite 4x fewer VMEM instructions. Segment density > instr count.
// LDS RULE (R22): dft re-read of the just-written 32KB tile from global is NOT
// cache-hot (+26MB HBM, 46->51us). LDS is the only guaranteed transpose medium.
// TLP RULE (R23): achieved occupancy (36%) is INVARIANT under cap changes (R8
// LDS=0, R9 8-wave 100% cap) -> floor is structural, not resource-capped.
// NT RULE (R24): nontemporal part2 didn't cut h FETCH and perturbed codegen.
// LDS-ONLY BARRIER (R26, -1us/emit): pre-dft __syncthreads drains vmcnt(0) (all
// 32 h-stores) but dft only reads LDS -> "s_waitcnt lgkmcnt(0); s_barrier".
// SETPRIO (R27): T5 regime check — emit/proj waves are barrier-free through the
// conv phase and blocks start staggered -> mixed phases per SIMD (the attn-like
// +4-7% regime, m191), not GEMM lockstep (m190 null). Wrap MFMA clusters.
// =============================================================================

__device__ __forceinline__ unsigned packsplit(float v) {
    unsigned u = __float_as_uint(v);
    unsigned hi = u & 0xffff0000u;
    float lo = v - __uint_as_float(hi);
    return hi | (__float_as_uint(lo) >> 16);
}
__device__ __forceinline__ void fsplit(float v, unsigned short& h, unsigned short& l) {
    unsigned u = __float_as_uint(v);
    h = (unsigned short)(u >> 16);
    float lof = v - __uint_as_float(u & 0xffff0000u);
    l = (unsigned short)(__float_as_uint(lof) >> 16);
}

// LDS-only barrier (R26): waits LDS ops, NOT outstanding global stores.
__device__ __forceinline__ void barrier_lds() {
    asm volatile("s_waitcnt lgkmcnt(0)\n\ts_barrier" ::: "memory");
}

// merged table build: blocks [0,512) = twiddle tables, [512,576) = conv-w pre-split.
__global__ void k_tables13(short* __restrict__ BTh, short* __restrict__ BTl,
                           short* __restrict__ BFhi, short* __restrict__ BFlo,
                           const float* __restrict__ cw,
                           short* __restrict__ CWFh, short* __restrict__ CWFl) {
    if (blockIdx.x < 512) {
        int idx = blockIdx.x * 256 + threadIdx.x;
        if (idx >= MODES * L) return;
        int k = idx >> 13;
        int l = idx & LMASK;
        int m = (k * l) & LMASK;
        float ang = 6.28318530717958647692f * ((float)m / (float)L);
        float s, c;
        sincosf(ang, &s, &c);
        unsigned short hh, ll;
        fsplit(c, hh, ll);
        BTh[(size_t)l * 32 + k] = (short)hh;  BTl[(size_t)l * 32 + k] = (short)ll;
        int sstep = l >> 5, qj = l & 31;
        int idx_re = ((sstep * 2 + 0) * 16 + k) * 32 + qj;
        BFhi[idx_re] = (short)hh;  BFlo[idx_re] = (short)ll;
        fsplit(s, hh, ll);
        BTh[(size_t)l * 32 + 16 + k] = (short)hh;  BTl[(size_t)l * 32 + 16 + k] = (short)ll;
        unsigned short nh, nl;
        fsplit(-s, nh, nl);
        int idx_im = ((sstep * 2 + 1) * 16 + k) * 32 + qj;
        BFhi[idx_im] = (short)nh;  BFlo[idx_im] = (short)nl;
    } else {
        int idx = (blockIdx.x - 512) * 256 + threadIdx.x;
        if (idx >= 4 * W * W) return;
        int layer = idx >> 12;
        int r = idx & 4095;
        int o = r >> 6, c = r & 63;
        int ot = o >> 4, n = o & 15, Kc = c >> 5, rest = c & 31;
        unsigned short hh, ll;
        fsplit(cw[idx], hh, ll);
        int di = layer * 4096 + ((ot * 2 + Kc) * 16 + n) * 32 + rest;
        CWFh[di] = (short)hh;  CWFl[di] = (short)ll;
    }
}

// ---- fused partial-DFT phase (shared by k_lift / k_combine_emit) ----
// HsL layout: 64 rows x 128 cols, word col XOR-swizzled by ((c&7)<<2).
__device__ __forceinline__ void dft_partial(const unsigned* HsL,
                                            const short* __restrict__ BFhi,
                                            const short* __restrict__ BFlo,
                                            float* __restrict__ part2,
                                            int b, int l0, int t) {
    int wv = t >> 6, lane = t & 63, quad = lane >> 4, n = lane & 15;
    int sbase = l0 >> 5;
    int c = wv * 16 + n;
    int swz = (c & 7) << 2;
    const unsigned* arow = HsL + c * 128;
    floatx4 accR = {0.f, 0.f, 0.f, 0.f}, accI = {0.f, 0.f, 0.f, 0.f};
#pragma unroll
    for (int ks = 0; ks < 4; ks++) {
        int col = quad * 8 + ks * 32;
        uint4 a0 = *(const uint4*)(arow + (col ^ swz));
        uint4 a1 = *(const uint4*)(arow + ((col + 4) ^ swz));
        unsigned av[8] = {a0.x, a0.y, a0.z, a0.w, a1.x, a1.y, a1.z, a1.w};
        union { short8 v; unsigned short u[8]; } ah, al;
#pragma unroll
        for (int j = 0; j < 8; j++) {
            ah.u[j] = (unsigned short)(av[j] >> 16);
            al.u[j] = (unsigned short)(av[j] & 0xffffu);
        }
        int s = sbase + ks;
        const short* bb = BFhi + ((size_t)(s * 2) * 16 + n) * 32 + quad * 8;
        const short* lb = BFlo + ((size_t)(s * 2) * 16 + n) * 32 + quad * 8;
        short8 BhR = *(const short8*)bb;
        short8 BlR = *(const short8*)lb;
        short8 BhI = *(const short8*)(bb + 512);
        short8 BlI = *(const short8*)(lb + 512);
        __builtin_amdgcn_s_setprio(1);             // R27
        accR = __builtin_amdgcn_mfma_f32_16x16x32_bf16(ah.v, BhR, accR, 0, 0, 0);
        accR = __builtin_amdgcn_mfma_f32_16x16x32_bf16(ah.v, BlR, accR, 0, 0, 0);
        accR = __builtin_amdgcn_mfma_f32_16x16x32_bf16(al.v, BhR, accR, 0, 0, 0);
        accI = __builtin_amdgcn_mfma_f32_16x16x32_bf16(ah.v, BhI, accI, 0, 0, 0);
        accI = __builtin_amdgcn_mfma_f32_16x16x32_bf16(ah.v, BlI, accI, 0, 0, 0);
        accI = __builtin_amdgcn_mfma_f32_16x16x32_bf16(al.v, BhI, accI, 0, 0, 0);
        __builtin_amdgcn_s_setprio(0);             // R27
    }
    float* pr = part2 + (size_t)(l0 >> 7) * 65536
                      + ((size_t)b * 64 + wv * 16 + quad * 4) * 32 + n;
#pragma unroll
    for (int r = 0; r < 4; r++) {
        pr[(size_t)r * 32]      = accR[r];
        pr[(size_t)r * 32 + 16] = accI[r];
    }
}

// lifting conv -> packed h (uint4-vectorized), fused with partial-DFT of layer 0
__global__ __launch_bounds__(256) void k_lift13(const float* __restrict__ x,
                                                const float* __restrict__ Pw,
                                                const float* __restrict__ Pb,
                                                unsigned* __restrict__ h,
                                                const short* __restrict__ BFhi,
                                                const short* __restrict__ BFlo,
                                                float* __restrict__ part2) {
    __shared__ unsigned HsL[64 * 128];
    int t = threadIdx.x;
    int b = blockIdx.y;
    int l0 = blockIdx.x * LT;
    int lq = t & 31, c8 = t >> 5;                  // thread: 4 consecutive l x 8 c
    float4 x0 = *((const float4*)(x + (size_t)(b * 2 + 0) * L + l0) + lq);
    float4 x1 = *((const float4*)(x + (size_t)(b * 2 + 1) * L + l0) + lq);
#pragma unroll
    for (int cc = 0; cc < 8; cc++) {
        int c = c8 * 8 + cc;
        float w0 = Pw[c * 2 + 0], w1 = Pw[c * 2 + 1], pb = Pb[c];
        uint4 pv;
        pv.x = packsplit(fmaf(w0, x0.x, fmaf(w1, x1.x, pb)));
        pv.y = packsplit(fmaf(w0, x0.y, fmaf(w1, x1.y, pb)));
        pv.z = packsplit(fmaf(w0, x0.z, fmaf(w1, x1.z, pb)));
        pv.w = packsplit(fmaf(w0, x0.w, fmaf(w1, x1.w, pb)));
        *(uint4*)(h + ((size_t)b * W + c) * L + l0 + lq * 4) = pv;
        *(uint4*)&HsL[c * 128 + ((lq * 4) ^ ((c & 7) << 2))] = pv;
    }
    barrier_lds();                                 // R26: h stores drain under dft
    dft_partial(HsL, BFhi, BFlo, part2, b, l0, t);
}

// reduce 64 chunks of part2 -> hf (hfr | hfi contiguous). 256 blocks, coalesced.
__global__ void k_red13(const float* __restrict__ part2, float* __restrict__ hf) {
    int idx = blockIdx.x * 256 + threadIdx.x;      // row*32 + kappa
    float s = 0.f;
#pragma unroll 16
    for (int c = 0; c < 64; c++) s += part2[(size_t)c * 65536 + idx];
    int row = idx >> 5, kp = idx & 31;
    if (kp < 16) hf[row * 16 + kp] = s;
    else         hf[32768 + row * 16 + (kp - 16)] = s;
}

// complex mode mix -> packed fragment-ready Gt (sign + irfft scale folded).
// (16,8) grid — tiny & L3-hot. Do not fuse (R10/12/15).
__global__ __launch_bounds__(256) void k_mix13(const float* __restrict__ hfr,
                                               const float* __restrict__ hfi,
                                               const float* __restrict__ kwr,
                                               const float* __restrict__ kwi,
                                               unsigned* __restrict__ Gt) {
    __shared__ float wrT[64 * 65], wiT[64 * 65];
    int t = threadIdx.x;
    int k = blockIdx.x;
    const float* wr = kwr + k * 4096;
    const float* wi = kwi + k * 4096;
    for (int i = t; i < 4096; i += 256) {
        int o = i >> 6, c = i & 63;
        wrT[c * 65 + o] = wr[i];
        wiT[c * 65 + o] = wi[i];
    }
    __syncthreads();
    int o = t & 63, bq = t >> 6;
    int b = blockIdx.y * 4 + bq;
    float accr = 0.f, acci = 0.f;
#pragma unroll 8
    for (int c = 0; c < W; c++) {
        float hr = hfr[(b * 64 + c) * 16 + k];
        float hi = hfi[(b * 64 + c) * 16 + k];
        float wrv = wrT[c * 65 + o], wiv = wiT[c * 65 + o];
        accr = fmaf(wrv, hr, fmaf(-wiv, hi, accr));
        acci = fmaf(wrv, hi, fmaf(wiv, hr, acci));
    }
    float sc = (k == 0) ? (1.f / (float)L) : (2.f / (float)L);
    float gi = (k == 0) ? 0.f : -acci * sc;
    Gt[((size_t)b * 64 + o) * 32 + k]      = packsplit(accr * sc);
    Gt[((size_t)b * 64 + o) * 32 + 16 + k] = packsplit(gi);
}

// branch-free erf (A&S 7.1.26)
__device__ __forceinline__ float erf_fast(float x) {
    float ax = fabsf(x);
    float tinv = __builtin_amdgcn_rcpf(fmaf(0.3275911f, ax, 1.f));
    float p = fmaf(1.061405429f, tinv, -1.453152027f);
    p = fmaf(p, tinv, 1.421413741f);
    p = fmaf(p, tinv, -0.284496736f);
    p = fmaf(p, tinv, 0.254829592f);
    p = p * tinv;
    float e = fmaf(-p, __expf(-ax * ax), 1.f);
    return copysignf(e, x);
}

// fused combine v21 (R27 = R12 + setprio around MFMA clusters): conv + irfft +
// gelu (MFMA split-bf16), DIRECT global B-fragment loads; stores stream in the
// compute loop; LDS-only pre-dft barrier (R26).
//  EMIT=1 (layers 0-2): write h + Hs; dft partials after the LDS-only barrier.
//  PROJ=1 (layer 3):    no h write, no LDS; Q-projection epilogue, barrier-free.
template<int EMIT, int PROJ>
__device__ __forceinline__ void combine_body(
    unsigned* __restrict__ h, const short* __restrict__ BTh, const short* __restrict__ BTl,
    const unsigned* __restrict__ Gt,
    const short* __restrict__ cwfh, const short* __restrict__ cwfl,
    const float* __restrict__ cb,
    const short* __restrict__ BFhi, const short* __restrict__ BFlo,
    float* __restrict__ part2,
    const float* __restrict__ Qw, const float* __restrict__ Qb,
    float* __restrict__ outbuf,
    unsigned* Hs) {
    int t = threadIdx.x;
    int b = blockIdx.y;
    int l0 = blockIdx.x * LT;

    int lane = t & 63, wv = t >> 6;
    int quad = lane >> 4, n = lane & 15;

    // B-fragments direct from global h (R16): 64B segments, lt pair covers full
    // 128B lines; wave-private l-slice -> in-place h update barrier-free.
    unsigned rawB[2][2][8];
    short8 Th[2], Tl[2];
#pragma unroll
    for (int lt = 0; lt < 2; lt++) {
        int lg = l0 + wv * 32 + lt * 16 + n;
        const unsigned* hb = h + (size_t)b * W * L + lg;
#pragma unroll
        for (int Kc = 0; Kc < 2; Kc++) {
#pragma unroll
            for (int j = 0; j < 8; j++) {
                int c = Kc * 32 + quad * 8 + j;
                rawB[lt][Kc][j] = hb[(size_t)c * L];
            }
        }
        Th[lt] = *(const short8*)(BTh + (size_t)lg * 32 + quad * 8);
        Tl[lt] = *(const short8*)(BTl + (size_t)lg * 32 + quad * 8);
    }
    short8 Bh[2][2], Bl[2][2];
#pragma unroll
    for (int lt = 0; lt < 2; lt++) {
#pragma unroll
        for (int Kc = 0; Kc < 2; Kc++) {
            union { short8 v; unsigned short u[8]; } uh, ul;
#pragma unroll
            for (int j = 0; j < 8; j++) {
                unsigned x = rawB[lt][Kc][j];
                uh.u[j] = (unsigned short)(x >> 16);
                ul.u[j] = (unsigned short)(x & 0xffffu);
            }
            Bh[lt][Kc] = uh.v; Bl[lt][Kc] = ul.v;
        }
    }

    float pacc[2] = {0.f, 0.f};                    // proj partials per lt

#pragma unroll 2
    for (int ot = 0; ot < 4; ot++) {
        int oa = ot * 16 + n;
        short8 Wh[2], Wl[2];
#pragma unroll
        for (int Kc = 0; Kc < 2; Kc++) {
            int wi = ((ot * 2 + Kc) * 16 + n) * 32 + quad * 8;
            Wh[Kc] = *(const short8*)(cwfh + wi);
            Wl[Kc] = *(const short8*)(cwfl + wi);
        }
        short8 Gh, Gl;
        {
            const uint4* gp = (const uint4*)(Gt + ((size_t)b * W + oa) * 32 + quad * 8);
            uint4 g0 = gp[0], g1 = gp[1];
            unsigned gv[8] = {g0.x, g0.y, g0.z, g0.w, g1.x, g1.y, g1.z, g1.w};
            union { short8 v; unsigned short u[8]; } ah, al;
#pragma unroll
            for (int j = 0; j < 8; j++) {
                ah.u[j] = (unsigned short)(gv[j] >> 16);
                al.u[j] = (unsigned short)(gv[j] & 0xffffu);
            }
            Gh = ah.v; Gl = al.v;
        }

#pragma unroll
        for (int lt = 0; lt < 2; lt++) {
            floatx4 acc = {0.f, 0.f, 0.f, 0.f};
            __builtin_amdgcn_s_setprio(1);         // R27
#pragma unroll
            for (int Kc = 0; Kc < 2; Kc++) {
                acc = __builtin_amdgcn_mfma_f32_16x16x32_bf16(Wh[Kc], Bh[lt][Kc], acc, 0, 0, 0);
                acc = __builtin_amdgcn_mfma_f32_16x16x32_bf16(Wh[Kc], Bl[lt][Kc], acc, 0, 0, 0);
                acc = __builtin_amdgcn_mfma_f32_16x16x32_bf16(Wl[Kc], Bh[lt][Kc], acc, 0, 0, 0);
            }
            acc = __builtin_amdgcn_mfma_f32_16x16x32_bf16(Gh, Th[lt], acc, 0, 0, 0);
            acc = __builtin_amdgcn_mfma_f32_16x16x32_bf16(Gh, Tl[lt], acc, 0, 0, 0);
            acc = __builtin_amdgcn_mfma_f32_16x16x32_bf16(Gl, Th[lt], acc, 0, 0, 0);
            __builtin_amdgcn_s_setprio(0);         // R27
            int lloc = wv * 32 + lt * 16 + n;
            int lg = l0 + lloc;
#pragma unroll
            for (int r = 0; r < 4; r++) {
                int od = ot * 16 + quad * 4 + r;
                float v = acc[r] + cb[od];
                float g = 0.5f * v * (1.f + erf_fast(v * 0.70710678118654752440f));
                if (PROJ) {
                    pacc[lt] = fmaf(Qw[od], g, pacc[lt]);
                } else {
                    unsigned p = packsplit(g);
                    h[((size_t)b * W + od) * L + lg] = p;
                    if (EMIT) Hs[od * 128 + (lloc ^ ((od & 7) << 2))] = p;
                }
            }
        }
    }
    if (EMIT) {
        barrier_lds();                             // R26: h stores drain under dft
        dft_partial(Hs, BFhi, BFlo, part2, b, l0, t);
    }
    if (PROJ) {
        float qb = Qb[0];
#pragma unroll
        for (int lt = 0; lt < 2; lt++) {
            float v = pacc[lt];
            v += __shfl_xor(v, 16, 64);            // sum quad pairs
            v += __shfl_xor(v, 32, 64);            // sum all 4 quads
            if (quad == 0)
                outbuf[(size_t)b * L + l0 + wv * 32 + lt * 16 + n] = v + qb;
        }
    }
}

__global__ __launch_bounds__(256, 4) void k_combine_emit13(
    unsigned* __restrict__ h, const short* __restrict__ BTh, const short* __restrict__ BTl,
    const unsigned* __restrict__ Gt,
    const short* __restrict__ cwfh, const short* __restrict__ cwfl,
    const float* __restrict__ cb,
    const short* __restrict__ BFhi, const short* __restrict__ BFlo,
    float* __restrict__ part2) {
    __shared__ unsigned Hs[64 * 128];
    combine_body<1, 0>(h, BTh, BTl, Gt, cwfh, cwfl, cb, BFhi, BFlo, part2,
                       nullptr, nullptr, nullptr, Hs);
}

__global__ __launch_bounds__(256, 4) void k_combine_proj13(
    unsigned* __restrict__ h, const short* __restrict__ BTh, const short* __restrict__ BTl,
    const unsigned* __restrict__ Gt,
    const short* __restrict__ cwfh, const short* __restrict__ cwfl,
    const float* __restrict__ cb,
    const float* __restrict__ Qw, const float* __restrict__ Qb,
    float* __restrict__ outbuf) {
    combine_body<0, 1>(h, BTh, BTl, Gt, cwfh, cwfl, cb, nullptr, nullptr, nullptr,
                       Qw, Qb, outbuf, nullptr);
}

extern "C" void kernel_launch(void* const* d_in, const int* in_sizes, int n_in,
                              void* d_out, int out_size, void* d_ws, size_t ws_size,
                              hipStream_t stream) {
    const float* x   = (const float*)d_in[0];
    const float* Pw  = (const float*)d_in[1];
    const float* Pb  = (const float*)d_in[2];
    const float* kwr = (const float*)d_in[3];
    const float* kwi = (const float*)d_in[4];
    const float* cw  = (const float*)d_in[5];
    const float* cb  = (const float*)d_in[6];
    const float* Qw  = (const float*)d_in[7];
    const float* Qb  = (const float*)d_in[8];

    float* ws = (float*)d_ws;
    unsigned* h    = (unsigned*)(ws + OFF_H);
    float*    hfr  = ws + OFF_HFR;
    float*    hfi  = ws + OFF_HFI;
    unsigned* Gt   = (unsigned*)(ws + OFF_GT);
    short*    BTh  = (short*)(ws + OFF_BTH);
    short*    BTl  = (short*)(ws + OFF_BTL);
    short*    BFhi = (short*)(ws + OFF_BFH);
    short*    BFlo = (short*)(ws + OFF_BFL);
    short*    CWFh = (short*)(ws + OFF_CWH);
    short*    CWFl = (short*)(ws + OFF_CWL);
    float*    part2 = ws + OFF_P2;

    k_tables13<<<512 + 64, 256, 0, stream>>>(BTh, BTl, BFhi, BFlo, cw, CWFh, CWFl);
    k_lift13<<<dim3(L / LT, B), 256, 0, stream>>>(x, Pw, Pb, h, BFhi, BFlo, part2);

    for (int i = 0; i < 4; i++) {
        k_red13<<<65536 / 256, 256, 0, stream>>>(part2, hfr);
        k_mix13<<<dim3(MODES, B / 4), 256, 0, stream>>>(hfr, hfi,
                                                        kwr + (size_t)i * MODES * W * W,
                                                        kwi + (size_t)i * MODES * W * W,
                                                        Gt);
        if (i < 3) {
            k_combine_emit13<<<dim3(L / LT, B), 256, 0, stream>>>(h, BTh, BTl, Gt,
                                                                  CWFh + (size_t)i * 4096,
                                                                  CWFl + (size_t)i * 4096,
                                                                  cb + (size_t)i * W,
                                                                  BFhi, BFlo, part2);
        } else {
            k_combine_proj13<<<dim3(L / LT, B), 256, 0, stream>>>(h, BTh, BTl, Gt,
                                                                  CWFh + (size_t)i * 4096,
                                                                  CWFl + (size_t)i * 4096,
                                                                  cb + (size_t)i * W,
                                                                  Qw, Qb, (float*)d_out);
        }
    }
}